// Round 1
// baseline (632.306 us; speedup 1.0000x reference)
//
#include <hip/hip_runtime.h>
#include <hip/hip_bf16.h>

typedef __hip_bfloat16 bf16;
typedef __bf16 bf16r;
typedef bf16r bf16x8 __attribute__((ext_vector_type(8)));
typedef bf16r bf16x4 __attribute__((ext_vector_type(4)));
typedef float f32x4 __attribute__((ext_vector_type(4)));
typedef short s16x4 __attribute__((ext_vector_type(4)));

#define T_SEQ 4096
#define C_DIM 1024
#define LD_QKV 3072
#define MB(x) ((size_t)(x) << 20)
// 0.125 (1/sqrt(64)) * log2(e): softmax runs in exp2 domain
#define SCL 0.18033688011112042f

static __device__ __forceinline__ unsigned short f2bf(float f) {
    bf16 h = (bf16)f;
    return *reinterpret_cast<unsigned short*>(&h);
}

// ---------------------------------------------------------------------------
// f32 -> bf16 weight convert, contiguous slice
// ---------------------------------------------------------------------------
__global__ __launch_bounds__(256) void cvt_w(const float* __restrict__ src, size_t eoff,
                                             ushort4* __restrict__ dst, int n4) {
    int i = blockIdx.x * 256 + threadIdx.x;
    const int stride = gridDim.x * 256;
    const float4* s = (const float4*)(src + eoff);
    for (; i < n4; i += stride) {
        float4 v = s[i];
        ushort4 o;
        o.x = f2bf(v.x); o.y = f2bf(v.y); o.z = f2bf(v.z); o.w = f2bf(v.w);
        dst[i] = o;
    }
}

// ---------------------------------------------------------------------------
// w2 column-slice convert: src f32 [1024][4096], cols [coff, coff+2048)
// -> dst bf16 [1024][2048] (compacted, ld = 2048).
// ---------------------------------------------------------------------------
__global__ __launch_bounds__(256) void cvt_w2h(const float* __restrict__ src, int coff,
                                               ushort4* __restrict__ dst) {
    const int i = blockIdx.x * 256 + threadIdx.x;
    const int row = i >> 9;
    const int c4 = i & 511;
    float4 v = *(const float4*)(src + (size_t)row * 4096 + coff + c4 * 4);
    ushort4 o;
    o.x = f2bf(v.x); o.y = f2bf(v.y); o.z = f2bf(v.z); o.w = f2bf(v.w);
    dst[i] = o;
}

// ---------------------------------------------------------------------------
// RMSNorm: f32 in, f32 weight, bf16 out. One block per row of 1024.
// ---------------------------------------------------------------------------
__global__ __launch_bounds__(256) void rmsnorm_k(const float* __restrict__ x,
                                                 const float* __restrict__ w,
                                                 bf16* __restrict__ out) {
    const int row = blockIdx.x;
    const int tid = threadIdx.x;
    const float* xr = x + (size_t)row * C_DIM;
    float v[4];
    float ss = 0.f;
#pragma unroll
    for (int i = 0; i < 4; i++) { v[i] = xr[tid * 4 + i]; ss += v[i] * v[i]; }
#pragma unroll
    for (int off = 32; off; off >>= 1) ss += __shfl_xor(ss, off);
    __shared__ float red[4];
    if ((tid & 63) == 0) red[tid >> 6] = ss;
    __syncthreads();
    const float tot = red[0] + red[1] + red[2] + red[3];
    const float scale = rsqrtf(tot * (1.0f / C_DIM) + 1e-6f);
#pragma unroll
    for (int i = 0; i < 4; i++) {
        const int c = tid * 4 + i;
        out[(size_t)row * C_DIM + c] = (bf16)(v[i] * scale * w[c]);
    }
}

// ---------------------------------------------------------------------------
// m97-structure GEMM: out[M,N] = A[M,K](lda) @ B[N,K](ldb)^T (+ epilogue)
// (unchanged)
// ---------------------------------------------------------------------------
template <int RESID, int OUTF32>
__global__ __launch_bounds__(256) void gemm128(const bf16* __restrict__ A, int lda,
                                               const bf16* __restrict__ B, int ldb,
                                               const void* __restrict__ resid,
                                               void* __restrict__ out,
                                               int N, int K) {
    __shared__ __align__(16) bf16r As[128 * 32];
    __shared__ __align__(16) bf16r Bs[128 * 32];
    const int tid = threadIdx.x;
    const int w = tid >> 6, lane = tid & 63;
    const int c = lane & 15, qd = lane >> 4;
    const int wm = w >> 1, wn = w & 1;
    const int mbase = blockIdx.y * 128;
    const int nbase = blockIdx.x * 128;

    const int srow = lane >> 2, schk = lane & 3;
    const bf16* gA = A + (size_t)(mbase + w * 32 + srow) * lda + schk * 8;
    const bf16* gB = B + (size_t)(nbase + w * 32 + srow) * ldb + schk * 8;

    f32x4 acc[4][4] = {};

    for (int k0 = 0; k0 < K; k0 += 32) {
        __syncthreads();
#pragma unroll
        for (int s = 0; s < 2; s++) {
            __builtin_amdgcn_global_load_lds(
                (const __attribute__((address_space(1))) void*)(gA + (size_t)(s * 16) * lda + k0),
                (__attribute__((address_space(3))) void*)&As[(w * 32 + s * 16) * 32], 16, 0, 0);
            __builtin_amdgcn_global_load_lds(
                (const __attribute__((address_space(1))) void*)(gB + (size_t)(s * 16) * ldb + k0),
                (__attribute__((address_space(3))) void*)&Bs[(w * 32 + s * 16) * 32], 16, 0, 0);
        }
        __syncthreads();

        bf16x8 a[4], b[4];
#pragma unroll
        for (int i = 0; i < 4; i++)
            a[i] = *(const bf16x8*)&As[(wm * 64 + i * 16 + c) * 32 + qd * 8];
#pragma unroll
        for (int j = 0; j < 4; j++)
            b[j] = *(const bf16x8*)&Bs[(wn * 64 + j * 16 + c) * 32 + qd * 8];
#pragma unroll
        for (int i = 0; i < 4; i++)
#pragma unroll
            for (int j = 0; j < 4; j++)
                acc[i][j] = __builtin_amdgcn_mfma_f32_16x16x32_bf16(a[i], b[j], acc[i][j], 0, 0, 0);
    }

#pragma unroll
    for (int i = 0; i < 4; i++) {
#pragma unroll
        for (int j = 0; j < 4; j++) {
            const int col = nbase + wn * 64 + j * 16 + c;
#pragma unroll
            for (int reg = 0; reg < 4; reg++) {
                const int row = mbase + wm * 64 + i * 16 + qd * 4 + reg;
                const size_t idx = (size_t)row * N + col;
                float v = acc[i][j][reg];
                if (RESID == 2) v += ((const float*)resid)[idx];
                if (RESID == 3) {
                    const float a1 = (float)((const bf16*)resid)[idx];
                    v = (a1 / (1.0f + __expf(-a1))) * v;
                }
                if (OUTF32)
                    ((float*)out)[idx] = v;
                else
                    ((bf16*)out)[idx] = (bf16)v;
            }
        }
    }
}

// ---------------------------------------------------------------------------
// Transpose a qkv section to [h][d][t]
// ---------------------------------------------------------------------------
__global__ __launch_bounds__(256) void build_tr(const bf16* __restrict__ qkv,
                                                bf16* __restrict__ dst, int soff) {
    const int h = blockIdx.y;
    const int tb = blockIdx.x;
    __shared__ bf16 tile[64][65];
    const int tx = threadIdx.x & 63;
    const int ty = threadIdx.x >> 6;
    for (int rr = ty; rr < 64; rr += 4)
        tile[rr][tx] = qkv[(size_t)(tb * 64 + rr) * LD_QKV + soff + h * 64 + tx];
    __syncthreads();
    for (int rr = ty; rr < 64; rr += 4)
        dst[((size_t)h * 64 + rr) * T_SEQ + tb * 64 + tx] = tile[tx][rr];
}

// ---------------------------------------------------------------------------
// MFMA flash attention v3. One block per (head, 64-row Q-tile); 4 waves x
// 16 Q-rows; KB=128 keys/iteration.
// S^T = K Q^T (16x16x32, A=K-frag, B=Q-frag) so row-softmax stats are
// per-lane scalars (q = lane&15).  KEY CHANGE vs v2: the S^T D-fragment
// (row = qd*4+r, col = c) is EXACTLY the B-fragment layout of
// v_mfma_f32_16x16x16_bf16 (k = qd*4+j, col = c), so the PV step
// O^T += VT P^T consumes P^T directly from registers — the 16 KB Ps LDS
// buffer, its 8 ds_write + 4 ds_read per chunk, and its bank conflicts are
// all gone.  LDS drops 48->32 KB: 4 blocks/CU, all 1024 blocks co-resident.
// Softmax runs in exp2 domain (SCL = 0.125*log2e folded into the scale mul;
// exp2f == raw v_exp_f32) with defer-max (skip alpha-rescale while
// mb - m <= 8, P bounded by 2^8 in f32 accum).
// VTs swizzle widened to 4-bit XOR (^ vr&15): PV b64 reads are 2-way (free).
// qb map: heavy = (qt ^ qt>>4)&1 mixes heavy/light blocks per CU under both
// stride-1 and stride-16 co-CU id patterns (full residency => no backfill).
// Only the last (diagonal) 128-key chunk needs causal masking (proof: for
// kb<nkb-1 max staged key = kb*128+127 < qb*64 = min q of the tile).
// ---------------------------------------------------------------------------
__global__ __launch_bounds__(256) void attn_mfma(const bf16* __restrict__ qkv,
                                                 const bf16* __restrict__ VT,
                                                 bf16* __restrict__ y) {
    __shared__ __align__(16) bf16r Ks[128][64];    // keys x d
    __shared__ __align__(16) bf16r VTs[64][128];   // d x keys

    const int w    = threadIdx.x >> 6;
    const int lane = threadIdx.x & 63;
    const int c    = lane & 15;
    const int qd   = lane >> 4;
    const int id   = blockIdx.x;
    const int h    = id & 15;          // head fastest: co-XCD blocks share K/V
    const int qt   = id >> 4;          // 0..63
    const int jj   = qt >> 1;
    const int qb   = ((qt ^ (qt >> 4)) & 1) ? (63 - jj) : jj;  // heavy/light mix
    const int qrow = qb * 64 + w * 16 + c;
    const int sw   = c & 7;            // xor swizzle key for K frag reads

    // Q B-frags: lane holds Q[qrow][ks*32 + qd*8 + j]
    bf16x8 qf[2];
    {
        const bf16* qp = qkv + (size_t)qrow * LD_QKV + h * 64;
        qf[0] = *(const bf16x8*)(qp + qd * 8);
        qf[1] = *(const bf16x8*)(qp + 32 + qd * 8);
    }

    f32x4 O[4] = {};                   // O^T: D[row=d=dt*16+qd*4+r][col=q=c]
    float m_i = -1e30f, l_i = 0.f;     // m_i in log2 domain
    const int nkb = (qb >> 1) + 1;     // 128-key chunks

    for (int kb = 0; kb < nkb; kb++) {
        __syncthreads();               // prior iteration's LDS reads done
#pragma unroll
        for (int ii = 0; ii < 4; ii++) {
            const int i = ii * 256 + threadIdx.x;
            const int kr = i >> 3, ch = i & 7;    // K: 128 rows x 8 chunks
            *(bf16x8*)&Ks[kr][(ch ^ (kr & 7)) * 8] =
                *(const bf16x8*)(qkv + (size_t)(kb * 128 + kr) * LD_QKV + C_DIM + h * 64 + ch * 8);
            const int vr = i >> 4, vch = i & 15;  // VT: 64 rows x 16 chunks
            *(bf16x8*)&VTs[vr][(vch ^ (vr & 15)) * 8] =
                *(const bf16x8*)(VT + ((size_t)h * 64 + vr) * T_SEQ + kb * 128 + vch * 8);
        }
        __syncthreads();

        // ---- S^T = K Q^T : rows = keys (kt*16 + qd*4 + r), cols = q (c) ----
        f32x4 ST[8];
#pragma unroll
        for (int kt = 0; kt < 8; kt++) {
            f32x4 z = {};
#pragma unroll
            for (int ks = 0; ks < 2; ks++) {
                bf16x8 kf = *(const bf16x8*)&Ks[kt * 16 + c][((ks * 4 + qd) ^ sw) * 8];
                z = __builtin_amdgcn_mfma_f32_16x16x32_bf16(kf, qf[ks], z, 0, 0, 0);
            }
            ST[kt] = z;
        }

        // ---- scale to log2 domain (+ causal mask on diagonal chunk) ----
        if (kb == nkb - 1) {
#pragma unroll
            for (int kt = 0; kt < 8; kt++)
#pragma unroll
                for (int r = 0; r < 4; r++) {
                    float s = ST[kt][r] * SCL;
                    if (kb * 128 + kt * 16 + qd * 4 + r > qrow) s = -1e30f;
                    ST[kt][r] = s;
                }
        } else {
#pragma unroll
            for (int kt = 0; kt < 8; kt++)
#pragma unroll
                for (int r = 0; r < 4; r++) ST[kt][r] *= SCL;
        }

        // ---- online softmax (exp2 domain), per-lane scalar stats ----
        float mb = -1e30f;
#pragma unroll
        for (int kt = 0; kt < 8; kt++)
#pragma unroll
            for (int r = 0; r < 4; r++) mb = fmaxf(mb, ST[kt][r]);
        mb = fmaxf(mb, __shfl_xor(mb, 16));
        mb = fmaxf(mb, __shfl_xor(mb, 32));

        bf16x4 pv[8];
        float rs = 0.f;
        if (__all(mb - m_i <= 8.0f)) {
            // defer-max: keep m_i, skip alpha-rescale; P bounded by 2^8
#pragma unroll
            for (int kt = 0; kt < 8; kt++)
#pragma unroll
                for (int r = 0; r < 4; r++) {
                    const float p = exp2f(ST[kt][r] - m_i);
                    pv[kt][r] = (bf16r)p;
                    rs += p;
                }
            rs += __shfl_xor(rs, 16);
            rs += __shfl_xor(rs, 32);
            l_i += rs;
        } else {
            const float mnew = fmaxf(m_i, mb);
            const float alpha = exp2f(m_i - mnew);
#pragma unroll
            for (int kt = 0; kt < 8; kt++)
#pragma unroll
                for (int r = 0; r < 4; r++) {
                    const float p = exp2f(ST[kt][r] - mnew);
                    pv[kt][r] = (bf16r)p;
                    rs += p;
                }
            rs += __shfl_xor(rs, 16);
            rs += __shfl_xor(rs, 32);
            l_i = l_i * alpha + rs;
            m_i = mnew;
#pragma unroll
            for (int dt = 0; dt < 4; dt++)
#pragma unroll
                for (int r = 0; r < 4; r++) O[dt][r] *= alpha;
        }

        // ---- O^T += VT P^T : 16x16x16, P^T straight from registers ----
#pragma unroll
        for (int kt = 0; kt < 8; kt++) {
            const s16x4 pf = __builtin_bit_cast(s16x4, pv[kt]);
#pragma unroll
            for (int dt = 0; dt < 4; dt++) {
                const s16x4 vf = *(const s16x4*)&VTs[dt * 16 + c]
                    [((kt * 2 + (qd >> 1)) ^ c) * 8 + (qd & 1) * 4];
                O[dt] = __builtin_amdgcn_mfma_f32_16x16x16bf16_1k(vf, pf, O[dt], 0, 0, 0);
            }
        }
    }

    // ---- epilogue: y[qrow][h*64 + d], 8B vector stores ----
    const float inv_l = 1.0f / l_i;
#pragma unroll
    for (int dt = 0; dt < 4; dt++) {
        bf16x4 ov;
#pragma unroll
        for (int r = 0; r < 4; r++) ov[r] = (bf16r)(O[dt][r] * inv_l);
        *(bf16x4*)(y + (size_t)qrow * C_DIM + h * 64 + dt * 16 + qd * 4) = ov;
    }
}

// ---------------------------------------------------------------------------
// launch.  Inputs f32, output f32.  ws peak = 56 MiB.
// ---------------------------------------------------------------------------
extern "C" void kernel_launch(void* const* d_in, const int* in_sizes, int n_in,
                              void* d_out, int out_size, void* d_ws, size_t ws_size,
                              hipStream_t stream) {
    const float* x        = (const float*)d_in[0];
    const float* attn_w   = (const float*)d_in[1];
    const float* ffn_w    = (const float*)d_in[2];
    const float* c_attn_w = (const float*)d_in[3];
    const float* c_proj_w = (const float*)d_in[4];
    const float* w1       = (const float*)d_in[5];
    const float* w2       = (const float*)d_in[6];
    const float* w3       = (const float*)d_in[7];
    float* xmid = (float*)d_out;

    char* ws = (char*)d_ws;
    bf16* cwA = (bf16*)(ws);
    bf16* cwP = (bf16*)(ws + MB(6));
    bf16* rms = (bf16*)(ws + MB(8));
    bf16* qkv = (bf16*)(ws + MB(16));
    bf16* VT  = (bf16*)(ws + MB(40));
    bf16* y   = (bf16*)(ws + MB(48));
    bf16* w1h = (bf16*)(ws + MB(16));
    bf16* w3h = (bf16*)(ws + MB(20));
    bf16* w2h = (bf16*)(ws + MB(24));
    bf16* h1h = (bf16*)(ws + MB(28));

    // 1. attention weights -> bf16
    cvt_w<<<512, 256, 0, stream>>>(c_attn_w, 0, (ushort4*)cwA, 3072 * 1024 / 4);
    cvt_w<<<512, 256, 0, stream>>>(c_proj_w, 0, (ushort4*)cwP, 1024 * 1024 / 4);
    // 2. rms1 = rmsnorm(x, attn_norm_w)
    rmsnorm_k<<<T_SEQ, 256, 0, stream>>>(x, attn_w, rms);
    // 3. qkv = rms1 @ c_attn^T   [4096, 3072]
    gemm128<0, 0><<<dim3(24, 32), 256, 0, stream>>>(rms, C_DIM, cwA, C_DIM, nullptr, qkv, 3072, 1024);
    // 4. VT (V transposed per head) + MFMA flash attention v3
    build_tr<<<dim3(64, 16), 256, 0, stream>>>(qkv, VT, 2 * C_DIM);
    attn_mfma<<<1024, 256, 0, stream>>>(qkv, VT, y);
    // 5. xmid = x + y @ c_proj^T   (f32, into d_out)
    gemm128<2, 1><<<dim3(8, 32), 256, 0, stream>>>(y, C_DIM, cwP, C_DIM, x, xmid, 1024, 1024);
    // 6. rms2 = rmsnorm(xmid, ffn_norm_w)
    rmsnorm_k<<<T_SEQ, 256, 0, stream>>>(xmid, ffn_w, rms);
    // 7. FFN in two Hf=2048 halves; w2-partials accumulate into xmid in place.
    for (int hh = 0; hh < 2; hh++) {
        cvt_w<<<512, 256, 0, stream>>>(w1, (size_t)hh * 2048 * 1024, (ushort4*)w1h, 2048 * 1024 / 4);
        gemm128<0, 0><<<dim3(16, 32), 256, 0, stream>>>(rms, C_DIM, w1h, C_DIM, nullptr, h1h, 2048, 1024);
        cvt_w<<<512, 256, 0, stream>>>(w3, (size_t)hh * 2048 * 1024, (ushort4*)w3h, 2048 * 1024 / 4);
        gemm128<3, 0><<<dim3(16, 32), 256, 0, stream>>>(rms, C_DIM, w3h, C_DIM, h1h, h1h, 2048, 1024);
        cvt_w2h<<<2048, 256, 0, stream>>>(w2, hh * 2048, (ushort4*)w2h);
        gemm128<2, 1><<<dim3(8, 32), 256, 0, stream>>>(h1h, 2048, w2h, 2048, xmid, xmid, 1024, 2048);
    }
}

// Round 2
// 582.839 us; speedup vs baseline: 1.0849x; 1.0849x over previous
//
#include <hip/hip_runtime.h>
#include <hip/hip_bf16.h>

typedef __hip_bfloat16 bf16;
typedef __bf16 bf16r;
typedef bf16r bf16x8 __attribute__((ext_vector_type(8)));
typedef bf16r bf16x4 __attribute__((ext_vector_type(4)));
typedef float f32x4 __attribute__((ext_vector_type(4)));

#define T_SEQ 4096
#define C_DIM 1024
#define LD_QKV 3072
#define MB(x) ((size_t)(x) << 20)
// 0.125 (1/sqrt(64)) * log2(e): softmax runs in exp2 domain
#define SCL 0.18033688011112042f

static __device__ __forceinline__ unsigned short f2bf(float f) {
    bf16 h = (bf16)f;
    return *reinterpret_cast<unsigned short*>(&h);
}

// ---------------------------------------------------------------------------
// f32 -> bf16 weight convert, contiguous slice
// ---------------------------------------------------------------------------
__global__ __launch_bounds__(256) void cvt_w(const float* __restrict__ src, size_t eoff,
                                             ushort4* __restrict__ dst, int n4) {
    int i = blockIdx.x * 256 + threadIdx.x;
    const int stride = gridDim.x * 256;
    const float4* s = (const float4*)(src + eoff);
    for (; i < n4; i += stride) {
        float4 v = s[i];
        ushort4 o;
        o.x = f2bf(v.x); o.y = f2bf(v.y); o.z = f2bf(v.z); o.w = f2bf(v.w);
        dst[i] = o;
    }
}

// ---------------------------------------------------------------------------
// w2 column-slice convert: src f32 [1024][4096], cols [coff, coff+2048)
// -> dst bf16 [1024][2048] (compacted, ld = 2048).
// ---------------------------------------------------------------------------
__global__ __launch_bounds__(256) void cvt_w2h(const float* __restrict__ src, int coff,
                                               ushort4* __restrict__ dst) {
    const int i = blockIdx.x * 256 + threadIdx.x;
    const int row = i >> 9;
    const int c4 = i & 511;
    float4 v = *(const float4*)(src + (size_t)row * 4096 + coff + c4 * 4);
    ushort4 o;
    o.x = f2bf(v.x); o.y = f2bf(v.y); o.z = f2bf(v.z); o.w = f2bf(v.w);
    dst[i] = o;
}

// ---------------------------------------------------------------------------
// RMSNorm: f32 in, f32 weight, bf16 out. One block per row of 1024.
// ---------------------------------------------------------------------------
__global__ __launch_bounds__(256) void rmsnorm_k(const float* __restrict__ x,
                                                 const float* __restrict__ w,
                                                 bf16* __restrict__ out) {
    const int row = blockIdx.x;
    const int tid = threadIdx.x;
    const float* xr = x + (size_t)row * C_DIM;
    float v[4];
    float ss = 0.f;
#pragma unroll
    for (int i = 0; i < 4; i++) { v[i] = xr[tid * 4 + i]; ss += v[i] * v[i]; }
#pragma unroll
    for (int off = 32; off; off >>= 1) ss += __shfl_xor(ss, off);
    __shared__ float red[4];
    if ((tid & 63) == 0) red[tid >> 6] = ss;
    __syncthreads();
    const float tot = red[0] + red[1] + red[2] + red[3];
    const float scale = rsqrtf(tot * (1.0f / C_DIM) + 1e-6f);
#pragma unroll
    for (int i = 0; i < 4; i++) {
        const int c = tid * 4 + i;
        out[(size_t)row * C_DIM + c] = (bf16)(v[i] * scale * w[c]);
    }
}

// ---------------------------------------------------------------------------
// m97-structure GEMM: out[M,N] = A[M,K](lda) @ B[N,K](ldb)^T (+ epilogue)
// (unchanged)
// ---------------------------------------------------------------------------
template <int RESID, int OUTF32>
__global__ __launch_bounds__(256) void gemm128(const bf16* __restrict__ A, int lda,
                                               const bf16* __restrict__ B, int ldb,
                                               const void* __restrict__ resid,
                                               void* __restrict__ out,
                                               int N, int K) {
    __shared__ __align__(16) bf16r As[128 * 32];
    __shared__ __align__(16) bf16r Bs[128 * 32];
    const int tid = threadIdx.x;
    const int w = tid >> 6, lane = tid & 63;
    const int c = lane & 15, qd = lane >> 4;
    const int wm = w >> 1, wn = w & 1;
    const int mbase = blockIdx.y * 128;
    const int nbase = blockIdx.x * 128;

    const int srow = lane >> 2, schk = lane & 3;
    const bf16* gA = A + (size_t)(mbase + w * 32 + srow) * lda + schk * 8;
    const bf16* gB = B + (size_t)(nbase + w * 32 + srow) * ldb + schk * 8;

    f32x4 acc[4][4] = {};

    for (int k0 = 0; k0 < K; k0 += 32) {
        __syncthreads();
#pragma unroll
        for (int s = 0; s < 2; s++) {
            __builtin_amdgcn_global_load_lds(
                (const __attribute__((address_space(1))) void*)(gA + (size_t)(s * 16) * lda + k0),
                (__attribute__((address_space(3))) void*)&As[(w * 32 + s * 16) * 32], 16, 0, 0);
            __builtin_amdgcn_global_load_lds(
                (const __attribute__((address_space(1))) void*)(gB + (size_t)(s * 16) * ldb + k0),
                (__attribute__((address_space(3))) void*)&Bs[(w * 32 + s * 16) * 32], 16, 0, 0);
        }
        __syncthreads();

        bf16x8 a[4], b[4];
#pragma unroll
        for (int i = 0; i < 4; i++)
            a[i] = *(const bf16x8*)&As[(wm * 64 + i * 16 + c) * 32 + qd * 8];
#pragma unroll
        for (int j = 0; j < 4; j++)
            b[j] = *(const bf16x8*)&Bs[(wn * 64 + j * 16 + c) * 32 + qd * 8];
#pragma unroll
        for (int i = 0; i < 4; i++)
#pragma unroll
            for (int j = 0; j < 4; j++)
                acc[i][j] = __builtin_amdgcn_mfma_f32_16x16x32_bf16(a[i], b[j], acc[i][j], 0, 0, 0);
    }

#pragma unroll
    for (int i = 0; i < 4; i++) {
#pragma unroll
        for (int j = 0; j < 4; j++) {
            const int col = nbase + wn * 64 + j * 16 + c;
#pragma unroll
            for (int reg = 0; reg < 4; reg++) {
                const int row = mbase + wm * 64 + i * 16 + qd * 4 + reg;
                const size_t idx = (size_t)row * N + col;
                float v = acc[i][j][reg];
                if (RESID == 2) v += ((const float*)resid)[idx];
                if (RESID == 3) {
                    const float a1 = (float)((const bf16*)resid)[idx];
                    v = (a1 / (1.0f + __expf(-a1))) * v;
                }
                if (OUTF32)
                    ((float*)out)[idx] = v;
                else
                    ((bf16*)out)[idx] = (bf16)v;
            }
        }
    }
}

// ---------------------------------------------------------------------------
// Transpose a qkv section to [h][d][t]
// ---------------------------------------------------------------------------
__global__ __launch_bounds__(256) void build_tr(const bf16* __restrict__ qkv,
                                                bf16* __restrict__ dst, int soff) {
    const int h = blockIdx.y;
    const int tb = blockIdx.x;
    __shared__ bf16 tile[64][65];
    const int tx = threadIdx.x & 63;
    const int ty = threadIdx.x >> 6;
    for (int rr = ty; rr < 64; rr += 4)
        tile[rr][tx] = qkv[(size_t)(tb * 64 + rr) * LD_QKV + soff + h * 64 + tx];
    __syncthreads();
    for (int rr = ty; rr < 64; rr += 4)
        dst[((size_t)h * 64 + rr) * T_SEQ + tb * 64 + tx] = tile[tx][rr];
}

// ---------------------------------------------------------------------------
// MFMA flash attention v4 = v2 structure + async-STAGE prefetch (T14) +
// exp2-domain softmax + defer-max.
//
// v3 post-mortem (round 1): register-direct P^T via 16x16x16 MFMA REGRESSED
// 131.8 -> 203 us.  16x16x16bf16_1k costs the same ~5 cyc as 16x16x32 (legacy
// half-K shape at half rate): PV went 16 -> 32 MFMA (MfmaUtil-time x1.55,
// exactly 48/32) and accumulate chains doubled in depth on a latency-bound
// kernel.  PV therefore reverts to the Ps-LDS 16x16x32 path.
//
// v4's actual-bottleneck fix: per chunk, v2 staged 64 KB K/VT global->LDS
// serially between two barriers -- every wave ate full L2 latency every
// chunk (FETCH_SIZE 12 MB total => K/V is L2/L3-resident, pure latency).
// Now chunk kb+1's global loads are issued into registers right after the
// compute barrier; the vmcnt wait lands at the ds_write at the TOP of the
// next iteration, so load latency hides under QK+softmax+PV of chunk kb.
//
// Softmax runs in exp2 domain (SCL = 0.125*log2e folded into the scale mul)
// with defer-max: while __all(mb - m_i <= 8), keep the old running max and
// skip the O-rescale (P bounded by 2^8; f32 accum, validated in round 1).
//
// LDS 48 KB -> 3 blocks/CU.  Only the last (diagonal) 128-key chunk needs
// causal masking (kb < nkb-1 => max staged key < qb*64 = min q of tile).
// ---------------------------------------------------------------------------
__global__ __launch_bounds__(256, 3) void attn_mfma(const bf16* __restrict__ qkv,
                                                    const bf16* __restrict__ VT,
                                                    bf16* __restrict__ y) {
    __shared__ __align__(16) bf16r Ks[128][64];    // keys x d
    __shared__ __align__(16) bf16r VTs[64][128];   // d x keys
    __shared__ __align__(16) bf16r Ps[4][16][128]; // per-wave q x keys

    const int tid  = threadIdx.x;
    const int w    = tid >> 6;
    const int lane = tid & 63;
    const int c    = lane & 15;
    const int qd   = lane >> 4;
    const int id   = blockIdx.x;
    const int h    = id & 15;          // head fastest: same-CU blocks differ in qb
    const int qt   = id >> 4;          // 0..63
    const int qb   = (qt & 1) ? (63 - (qt >> 1)) : (qt >> 1);  // heavy/light pairing
    const int qrow = qb * 64 + w * 16 + c;
    const int sw   = c & 7;            // xor swizzle key for frag reads

    // Q B-frags: lane holds Q[qrow][ks*32 + qd*8 + j]
    bf16x8 qf[2];
    {
        const bf16* qp = qkv + (size_t)qrow * LD_QKV + h * 64;
        qf[0] = *(const bf16x8*)(qp + qd * 8);
        qf[1] = *(const bf16x8*)(qp + 32 + qd * 8);
    }

    // per-thread staging coordinates (same for every chunk)
    const int skr = tid >> 3, sch = tid & 7;      // K: 128 rows x 8 chunks (i = ii*256+tid -> kr = skr + ii*32)
    const int svr = tid >> 4, svch = tid & 15;    // VT: 64 rows x 16 chunks (vr = svr + ii*16)

    f32x4 O[4] = {};                   // O^T: D[row=d=dt*16+qd*4+r][col=q=c]
    float m_i = -1e30f, l_i = 0.f;     // m_i in log2 domain
    const int nkb = (qb >> 1) + 1;     // 128-key chunks

    // ---- prologue: load chunk 0 into registers ----
    bf16x8 kreg[4], vreg[4];
#pragma unroll
    for (int ii = 0; ii < 4; ii++) {
        const int kr = skr + ii * 32;
        kreg[ii] = *(const bf16x8*)(qkv + (size_t)kr * LD_QKV + C_DIM + h * 64 + sch * 8);
        const int vr = svr + ii * 16;
        vreg[ii] = *(const bf16x8*)(VT + ((size_t)h * 64 + vr) * T_SEQ + svch * 8);
    }

    for (int kb = 0; kb < nkb; kb++) {
        __syncthreads();               // prior iteration's LDS reads done
        // ---- write staged registers -> LDS (vmcnt wait lands here) ----
#pragma unroll
        for (int ii = 0; ii < 4; ii++) {
            const int kr = skr + ii * 32;
            *(bf16x8*)&Ks[kr][(sch ^ (kr & 7)) * 8] = kreg[ii];
            const int vr = svr + ii * 16;
            *(bf16x8*)&VTs[vr][(svch ^ (vr & 7)) * 8] = vreg[ii];
        }
        __syncthreads();
        // ---- issue chunk kb+1 global loads (latency hides under compute) ----
        if (kb + 1 < nkb) {
#pragma unroll
            for (int ii = 0; ii < 4; ii++) {
                const int kr = skr + ii * 32;
                kreg[ii] = *(const bf16x8*)(qkv + (size_t)((kb + 1) * 128 + kr) * LD_QKV + C_DIM + h * 64 + sch * 8);
                const int vr = svr + ii * 16;
                vreg[ii] = *(const bf16x8*)(VT + ((size_t)h * 64 + vr) * T_SEQ + (kb + 1) * 128 + svch * 8);
            }
        }

        // ---- S^T = K Q^T : rows = keys (kt*16 + qd*4 + r), cols = q (c) ----
        f32x4 ST[8];
#pragma unroll
        for (int kt = 0; kt < 8; kt++) {
            f32x4 z = {};
#pragma unroll
            for (int ks = 0; ks < 2; ks++) {
                bf16x8 kf = *(const bf16x8*)&Ks[kt * 16 + c][((ks * 4 + qd) ^ sw) * 8];
                z = __builtin_amdgcn_mfma_f32_16x16x32_bf16(kf, qf[ks], z, 0, 0, 0);
            }
            ST[kt] = z;
        }

        // ---- scale to log2 domain (+ causal mask on diagonal chunk) ----
        if (kb == nkb - 1) {
#pragma unroll
            for (int kt = 0; kt < 8; kt++)
#pragma unroll
                for (int r = 0; r < 4; r++) {
                    float s = ST[kt][r] * SCL;
                    if (kb * 128 + kt * 16 + qd * 4 + r > qrow) s = -1e30f;
                    ST[kt][r] = s;
                }
        } else {
#pragma unroll
            for (int kt = 0; kt < 8; kt++)
#pragma unroll
                for (int r = 0; r < 4; r++) ST[kt][r] *= SCL;
        }

        // ---- online softmax (exp2 domain), per-lane scalar stats ----
        float mb = -1e30f;
#pragma unroll
        for (int kt = 0; kt < 8; kt++)
#pragma unroll
            for (int r = 0; r < 4; r++) mb = fmaxf(mb, ST[kt][r]);
        mb = fmaxf(mb, __shfl_xor(mb, 16));
        mb = fmaxf(mb, __shfl_xor(mb, 32));

        bf16x4 pv[8];
        float rs = 0.f;
        if (__all(mb - m_i <= 8.0f)) {
            // defer-max: keep m_i, skip alpha-rescale; P bounded by 2^8
#pragma unroll
            for (int kt = 0; kt < 8; kt++)
#pragma unroll
                for (int r = 0; r < 4; r++) {
                    const float p = exp2f(ST[kt][r] - m_i);
                    pv[kt][r] = (bf16r)p;
                    rs += p;
                }
            rs += __shfl_xor(rs, 16);
            rs += __shfl_xor(rs, 32);
            l_i += rs;
        } else {
            const float mnew = fmaxf(m_i, mb);
            const float alpha = exp2f(m_i - mnew);
#pragma unroll
            for (int kt = 0; kt < 8; kt++)
#pragma unroll
                for (int r = 0; r < 4; r++) {
                    const float p = exp2f(ST[kt][r] - mnew);
                    pv[kt][r] = (bf16r)p;
                    rs += p;
                }
            rs += __shfl_xor(rs, 16);
            rs += __shfl_xor(rs, 32);
            l_i = l_i * alpha + rs;
            m_i = mnew;
#pragma unroll
            for (int dt = 0; dt < 4; dt++)
#pragma unroll
                for (int r = 0; r < 4; r++) O[dt][r] *= alpha;
        }

        // ---- P^T -> Ps[q][key] via 8B vector writes (wave-private) ----
#pragma unroll
        for (int kt = 0; kt < 8; kt++) {
            const int phys = (kt * 2 + (qd >> 1)) ^ sw;  // 16B-chunk swizzle
            *(bf16x4*)&Ps[w][c][phys * 8 + (qd & 1) * 4] = pv[kt];
        }

        // ---- O^T += VT P^T (16x16x32) ----
#pragma unroll
        for (int ks = 0; ks < 4; ks++) {
            bf16x8 pf = *(const bf16x8*)&Ps[w][c][((ks * 4 + qd) ^ sw) * 8];
#pragma unroll
            for (int dt = 0; dt < 4; dt++) {
                bf16x8 vf = *(const bf16x8*)&VTs[dt * 16 + c][((ks * 4 + qd) ^ sw) * 8];
                O[dt] = __builtin_amdgcn_mfma_f32_16x16x32_bf16(vf, pf, O[dt], 0, 0, 0);
            }
        }
    }

    // ---- epilogue: y[qrow][h*64 + d], 8B vector stores ----
    const float inv_l = 1.0f / l_i;
#pragma unroll
    for (int dt = 0; dt < 4; dt++) {
        bf16x4 ov;
#pragma unroll
        for (int r = 0; r < 4; r++) ov[r] = (bf16r)(O[dt][r] * inv_l);
        *(bf16x4*)(y + (size_t)qrow * C_DIM + h * 64 + dt * 16 + qd * 4) = ov;
    }
}

// ---------------------------------------------------------------------------
// launch.  Inputs f32, output f32.  ws peak = 56 MiB.
// ---------------------------------------------------------------------------
extern "C" void kernel_launch(void* const* d_in, const int* in_sizes, int n_in,
                              void* d_out, int out_size, void* d_ws, size_t ws_size,
                              hipStream_t stream) {
    const float* x        = (const float*)d_in[0];
    const float* attn_w   = (const float*)d_in[1];
    const float* ffn_w    = (const float*)d_in[2];
    const float* c_attn_w = (const float*)d_in[3];
    const float* c_proj_w = (const float*)d_in[4];
    const float* w1       = (const float*)d_in[5];
    const float* w2       = (const float*)d_in[6];
    const float* w3       = (const float*)d_in[7];
    float* xmid = (float*)d_out;

    char* ws = (char*)d_ws;
    bf16* cwA = (bf16*)(ws);
    bf16* cwP = (bf16*)(ws + MB(6));
    bf16* rms = (bf16*)(ws + MB(8));
    bf16* qkv = (bf16*)(ws + MB(16));
    bf16* VT  = (bf16*)(ws + MB(40));
    bf16* y   = (bf16*)(ws + MB(48));
    bf16* w1h = (bf16*)(ws + MB(16));
    bf16* w3h = (bf16*)(ws + MB(20));
    bf16* w2h = (bf16*)(ws + MB(24));
    bf16* h1h = (bf16*)(ws + MB(28));

    // 1. attention weights -> bf16
    cvt_w<<<512, 256, 0, stream>>>(c_attn_w, 0, (ushort4*)cwA, 3072 * 1024 / 4);
    cvt_w<<<512, 256, 0, stream>>>(c_proj_w, 0, (ushort4*)cwP, 1024 * 1024 / 4);
    // 2. rms1 = rmsnorm(x, attn_norm_w)
    rmsnorm_k<<<T_SEQ, 256, 0, stream>>>(x, attn_w, rms);
    // 3. qkv = rms1 @ c_attn^T   [4096, 3072]
    gemm128<0, 0><<<dim3(24, 32), 256, 0, stream>>>(rms, C_DIM, cwA, C_DIM, nullptr, qkv, 3072, 1024);
    // 4. VT (V transposed per head) + MFMA flash attention v4
    build_tr<<<dim3(64, 16), 256, 0, stream>>>(qkv, VT, 2 * C_DIM);
    attn_mfma<<<1024, 256, 0, stream>>>(qkv, VT, y);
    // 5. xmid = x + y @ c_proj^T   (f32, into d_out)
    gemm128<2, 1><<<dim3(8, 32), 256, 0, stream>>>(y, C_DIM, cwP, C_DIM, x, xmid, 1024, 1024);
    // 6. rms2 = rmsnorm(xmid, ffn_norm_w)
    rmsnorm_k<<<T_SEQ, 256, 0, stream>>>(xmid, ffn_w, rms);
    // 7. FFN in two Hf=2048 halves; w2-partials accumulate into xmid in place.
    for (int hh = 0; hh < 2; hh++) {
        cvt_w<<<512, 256, 0, stream>>>(w1, (size_t)hh * 2048 * 1024, (ushort4*)w1h, 2048 * 1024 / 4);
        gemm128<0, 0><<<dim3(16, 32), 256, 0, stream>>>(rms, C_DIM, w1h, C_DIM, nullptr, h1h, 2048, 1024);
        cvt_w<<<512, 256, 0, stream>>>(w3, (size_t)hh * 2048 * 1024, (ushort4*)w3h, 2048 * 1024 / 4);
        gemm128<3, 0><<<dim3(16, 32), 256, 0, stream>>>(rms, C_DIM, w3h, C_DIM, h1h, h1h, 2048, 1024);
        cvt_w2h<<<2048, 256, 0, stream>>>(w2, hh * 2048, (ushort4*)w2h);
        gemm128<2, 1><<<dim3(8, 32), 256, 0, stream>>>(h1h, 2048, w2h, 2048, xmid, xmid, 1024, 2048);
    }
}

// Round 3
// 578.971 us; speedup vs baseline: 1.0921x; 1.0067x over previous
//
#include <hip/hip_runtime.h>
#include <hip/hip_bf16.h>

typedef __hip_bfloat16 bf16;
typedef __bf16 bf16r;
typedef bf16r bf16x8 __attribute__((ext_vector_type(8)));
typedef bf16r bf16x4 __attribute__((ext_vector_type(4)));
typedef float f32x4 __attribute__((ext_vector_type(4)));

#define T_SEQ 4096
#define C_DIM 1024
#define LD_QKV 3072
#define MB(x) ((size_t)(x) << 20)
// 0.125 (1/sqrt(64)) * log2(e): softmax runs in exp2 domain
#define SCL 0.18033688011112042f

static __device__ __forceinline__ unsigned short f2bf(float f) {
    bf16 h = (bf16)f;
    return *reinterpret_cast<unsigned short*>(&h);
}

// ---------------------------------------------------------------------------
// f32 -> bf16 weight convert, contiguous slice
// ---------------------------------------------------------------------------
__global__ __launch_bounds__(256) void cvt_w(const float* __restrict__ src, size_t eoff,
                                             ushort4* __restrict__ dst, int n4) {
    int i = blockIdx.x * 256 + threadIdx.x;
    const int stride = gridDim.x * 256;
    const float4* s = (const float4*)(src + eoff);
    for (; i < n4; i += stride) {
        float4 v = s[i];
        ushort4 o;
        o.x = f2bf(v.x); o.y = f2bf(v.y); o.z = f2bf(v.z); o.w = f2bf(v.w);
        dst[i] = o;
    }
}

// ---------------------------------------------------------------------------
// w2 column-slice convert: src f32 [1024][4096], cols [coff, coff+2048)
// -> dst bf16 [1024][2048] (compacted, ld = 2048).
// ---------------------------------------------------------------------------
__global__ __launch_bounds__(256) void cvt_w2h(const float* __restrict__ src, int coff,
                                               ushort4* __restrict__ dst) {
    const int i = blockIdx.x * 256 + threadIdx.x;
    const int row = i >> 9;
    const int c4 = i & 511;
    float4 v = *(const float4*)(src + (size_t)row * 4096 + coff + c4 * 4);
    ushort4 o;
    o.x = f2bf(v.x); o.y = f2bf(v.y); o.z = f2bf(v.z); o.w = f2bf(v.w);
    dst[i] = o;
}

// ---------------------------------------------------------------------------
// RMSNorm: f32 in, f32 weight, bf16 out. One block per row of 1024.
// ---------------------------------------------------------------------------
__global__ __launch_bounds__(256) void rmsnorm_k(const float* __restrict__ x,
                                                 const float* __restrict__ w,
                                                 bf16* __restrict__ out) {
    const int row = blockIdx.x;
    const int tid = threadIdx.x;
    const float* xr = x + (size_t)row * C_DIM;
    float v[4];
    float ss = 0.f;
#pragma unroll
    for (int i = 0; i < 4; i++) { v[i] = xr[tid * 4 + i]; ss += v[i] * v[i]; }
#pragma unroll
    for (int off = 32; off; off >>= 1) ss += __shfl_xor(ss, off);
    __shared__ float red[4];
    if ((tid & 63) == 0) red[tid >> 6] = ss;
    __syncthreads();
    const float tot = red[0] + red[1] + red[2] + red[3];
    const float scale = rsqrtf(tot * (1.0f / C_DIM) + 1e-6f);
#pragma unroll
    for (int i = 0; i < 4; i++) {
        const int c = tid * 4 + i;
        out[(size_t)row * C_DIM + c] = (bf16)(v[i] * scale * w[c]);
    }
}

// ---------------------------------------------------------------------------
// m97-structure GEMM: out[M,N] = A[M,K](lda) @ B[N,K](ldb)^T (+ epilogue)
// (unchanged)
// ---------------------------------------------------------------------------
template <int RESID, int OUTF32>
__global__ __launch_bounds__(256) void gemm128(const bf16* __restrict__ A, int lda,
                                               const bf16* __restrict__ B, int ldb,
                                               const void* __restrict__ resid,
                                               void* __restrict__ out,
                                               int N, int K) {
    __shared__ __align__(16) bf16r As[128 * 32];
    __shared__ __align__(16) bf16r Bs[128 * 32];
    const int tid = threadIdx.x;
    const int w = tid >> 6, lane = tid & 63;
    const int c = lane & 15, qd = lane >> 4;
    const int wm = w >> 1, wn = w & 1;
    const int mbase = blockIdx.y * 128;
    const int nbase = blockIdx.x * 128;

    const int srow = lane >> 2, schk = lane & 3;
    const bf16* gA = A + (size_t)(mbase + w * 32 + srow) * lda + schk * 8;
    const bf16* gB = B + (size_t)(nbase + w * 32 + srow) * ldb + schk * 8;

    f32x4 acc[4][4] = {};

    for (int k0 = 0; k0 < K; k0 += 32) {
        __syncthreads();
#pragma unroll
        for (int s = 0; s < 2; s++) {
            __builtin_amdgcn_global_load_lds(
                (const __attribute__((address_space(1))) void*)(gA + (size_t)(s * 16) * lda + k0),
                (__attribute__((address_space(3))) void*)&As[(w * 32 + s * 16) * 32], 16, 0, 0);
            __builtin_amdgcn_global_load_lds(
                (const __attribute__((address_space(1))) void*)(gB + (size_t)(s * 16) * ldb + k0),
                (__attribute__((address_space(3))) void*)&Bs[(w * 32 + s * 16) * 32], 16, 0, 0);
        }
        __syncthreads();

        bf16x8 a[4], b[4];
#pragma unroll
        for (int i = 0; i < 4; i++)
            a[i] = *(const bf16x8*)&As[(wm * 64 + i * 16 + c) * 32 + qd * 8];
#pragma unroll
        for (int j = 0; j < 4; j++)
            b[j] = *(const bf16x8*)&Bs[(wn * 64 + j * 16 + c) * 32 + qd * 8];
#pragma unroll
        for (int i = 0; i < 4; i++)
#pragma unroll
            for (int j = 0; j < 4; j++)
                acc[i][j] = __builtin_amdgcn_mfma_f32_16x16x32_bf16(a[i], b[j], acc[i][j], 0, 0, 0);
    }

#pragma unroll
    for (int i = 0; i < 4; i++) {
#pragma unroll
        for (int j = 0; j < 4; j++) {
            const int col = nbase + wn * 64 + j * 16 + c;
#pragma unroll
            for (int reg = 0; reg < 4; reg++) {
                const int row = mbase + wm * 64 + i * 16 + qd * 4 + reg;
                const size_t idx = (size_t)row * N + col;
                float v = acc[i][j][reg];
                if (RESID == 2) v += ((const float*)resid)[idx];
                if (RESID == 3) {
                    const float a1 = (float)((const bf16*)resid)[idx];
                    v = (a1 / (1.0f + __expf(-a1))) * v;
                }
                if (OUTF32)
                    ((float*)out)[idx] = v;
                else
                    ((bf16*)out)[idx] = (bf16)v;
            }
        }
    }
}

// ---------------------------------------------------------------------------
// Transpose a qkv section to [h][d][t]
// ---------------------------------------------------------------------------
__global__ __launch_bounds__(256) void build_tr(const bf16* __restrict__ qkv,
                                                bf16* __restrict__ dst, int soff) {
    const int h = blockIdx.y;
    const int tb = blockIdx.x;
    __shared__ bf16 tile[64][65];
    const int tx = threadIdx.x & 63;
    const int ty = threadIdx.x >> 6;
    for (int rr = ty; rr < 64; rr += 4)
        tile[rr][tx] = qkv[(size_t)(tb * 64 + rr) * LD_QKV + soff + h * 64 + tx];
    __syncthreads();
    for (int rr = ty; rr < 64; rr += 4)
        dst[((size_t)h * 64 + rr) * T_SEQ + tb * 64 + tx] = tile[tx][rr];
}

// ---------------------------------------------------------------------------
// MFMA flash attention v5 = v2 compute structure + DOUBLE-BUFFERED
// global_load_lds staging (pre-swizzled global source, linear LDS dest) +
// exp2-domain softmax + defer-max.
//
// Round-2 post-mortem: v4's register-round-trip prefetch spilled to scratch
// (WRITE_SIZE 8.2 -> 23.9 MB, VGPR 96 -> 84: compiler demoted kreg/vreg) and
// regressed.  v5 keeps NO data in registers: chunk kb+1 streams directly
// global->LDS into buffer cur^1 via global_load_lds while compute runs on
// buffer cur.  The compiler's s_waitcnt vmcnt(0) before each s_barrier is
// the only drain point, one iteration later -- full QK+softmax+PV hides the
// L2 latency (FETCH 12 MB total => K/V is L2-resident, pure latency).
//
// Swizzle preservation (m173 pattern): LDS dest stays linear (gload_lds
// writes base + lane*16); the per-lane GLOBAL source address carries the
// XOR: lane covering physical chunk p of row r fetches global chunk
// p ^ (r&7).  This reproduces v2's proven layout exactly, so all frag
// reads are unchanged.  One barrier per iteration (v2 had two).
//
// LDS 80 KB -> 2 blocks/CU (measured occupancy never hit the 3-block cap).
// Only the last (diagonal) 128-key chunk needs causal masking.
// ---------------------------------------------------------------------------
__global__ __launch_bounds__(256) void attn_mfma(const bf16* __restrict__ qkv,
                                                 const bf16* __restrict__ VT,
                                                 bf16* __restrict__ y) {
    __shared__ __align__(16) bf16r Ks[2][128][64];    // keys x d, double-buffered
    __shared__ __align__(16) bf16r VTs[2][64][128];   // d x keys, double-buffered
    __shared__ __align__(16) bf16r Ps[4][16][128];    // per-wave q x keys

    const int tid  = threadIdx.x;
    const int w    = tid >> 6;
    const int lane = tid & 63;
    const int c    = lane & 15;
    const int qd   = lane >> 4;
    const int id   = blockIdx.x;
    const int h    = id & 15;          // head fastest: same-CU blocks differ in qb
    const int qt   = id >> 4;          // 0..63
    const int qb   = (qt & 1) ? (63 - (qt >> 1)) : (qt >> 1);  // heavy/light pairing
    const int qrow = qb * 64 + w * 16 + c;
    const int sw   = c & 7;            // xor swizzle key for frag reads

    // Q B-frags: lane holds Q[qrow][ks*32 + qd*8 + j]
    bf16x8 qf[2];
    {
        const bf16* qp = qkv + (size_t)qrow * LD_QKV + h * 64;
        qf[0] = *(const bf16x8*)(qp + qd * 8);
        qf[1] = *(const bf16x8*)(qp + 32 + qd * 8);
    }

    // Per-lane staging coords. Each global_load_lds covers 64 lanes x 16B =
    // 1 KB. K buffer: 16 groups of 8 rows (128B/row); lane l -> row l>>3,
    // physical chunk l&7. VT buffer: 16 groups of 4 rows (256B/row); lane
    // l -> row l>>4, physical chunk l&15. Source address pre-swizzled.
    const int k_ri = lane >> 3, k_pc = lane & 7;
    const int v_ri = lane >> 4, v_pc = lane & 15;

    auto stage = [&](int kb, int buf) {
#pragma unroll
        for (int ii = 0; ii < 4; ii++) {
            const int grp = w * 4 + ii;             // 0..15
            const int kr = grp * 8 + k_ri;          // 0..127
            const int kch = k_pc ^ (kr & 7);        // pre-swizzled global chunk
            __builtin_amdgcn_global_load_lds(
                (const __attribute__((address_space(1))) void*)
                    (qkv + (size_t)(kb * 128 + kr) * LD_QKV + C_DIM + h * 64 + kch * 8),
                (__attribute__((address_space(3))) void*)&Ks[buf][grp * 8][0], 16, 0, 0);
            const int vr = grp * 4 + v_ri;          // 0..63
            const int vch = v_pc ^ (vr & 7);        // pre-swizzled global chunk
            __builtin_amdgcn_global_load_lds(
                (const __attribute__((address_space(1))) void*)
                    (VT + ((size_t)h * 64 + vr) * T_SEQ + kb * 128 + vch * 8),
                (__attribute__((address_space(3))) void*)&VTs[buf][grp * 4][0], 16, 0, 0);
        }
    };

    f32x4 O[4] = {};                   // O^T: D[row=d=dt*16+qd*4+r][col=q=c]
    float m_i = -1e30f, l_i = 0.f;     // m_i in log2 domain
    const int nkb = (qb >> 1) + 1;     // 128-key chunks

    // ---- prologue: stream chunk 0 into buffer 0 ----
    stage(0, 0);

    int cur = 0;
    for (int kb = 0; kb < nkb; kb++) {
        // Drain in-flight gload_lds (buf[cur] ready) and retire all waves'
        // prior-iteration LDS reads of buf[cur^1] before it is overwritten.
        asm volatile("s_waitcnt vmcnt(0)" ::: "memory");
        __syncthreads();
        if (kb + 1 < nkb) stage(kb + 1, cur ^ 1);   // flies under this chunk's compute

        // ---- S^T = K Q^T : rows = keys (kt*16 + qd*4 + r), cols = q (c) ----
        f32x4 ST[8];
#pragma unroll
        for (int kt = 0; kt < 8; kt++) {
            f32x4 z = {};
#pragma unroll
            for (int ks = 0; ks < 2; ks++) {
                bf16x8 kf = *(const bf16x8*)&Ks[cur][kt * 16 + c][((ks * 4 + qd) ^ sw) * 8];
                z = __builtin_amdgcn_mfma_f32_16x16x32_bf16(kf, qf[ks], z, 0, 0, 0);
            }
            ST[kt] = z;
        }

        // ---- scale to log2 domain (+ causal mask on diagonal chunk) ----
        if (kb == nkb - 1) {
#pragma unroll
            for (int kt = 0; kt < 8; kt++)
#pragma unroll
                for (int r = 0; r < 4; r++) {
                    float s = ST[kt][r] * SCL;
                    if (kb * 128 + kt * 16 + qd * 4 + r > qrow) s = -1e30f;
                    ST[kt][r] = s;
                }
        } else {
#pragma unroll
            for (int kt = 0; kt < 8; kt++)
#pragma unroll
                for (int r = 0; r < 4; r++) ST[kt][r] *= SCL;
        }

        // ---- online softmax (exp2 domain), per-lane scalar stats ----
        float mb = -1e30f;
#pragma unroll
        for (int kt = 0; kt < 8; kt++)
#pragma unroll
            for (int r = 0; r < 4; r++) mb = fmaxf(mb, ST[kt][r]);
        mb = fmaxf(mb, __shfl_xor(mb, 16));
        mb = fmaxf(mb, __shfl_xor(mb, 32));

        bf16x4 pv[8];
        float rs = 0.f;
        if (__all(mb - m_i <= 8.0f)) {
            // defer-max: keep m_i, skip alpha-rescale; P bounded by 2^8
#pragma unroll
            for (int kt = 0; kt < 8; kt++)
#pragma unroll
                for (int r = 0; r < 4; r++) {
                    const float p = exp2f(ST[kt][r] - m_i);
                    pv[kt][r] = (bf16r)p;
                    rs += p;
                }
            rs += __shfl_xor(rs, 16);
            rs += __shfl_xor(rs, 32);
            l_i += rs;
        } else {
            const float mnew = fmaxf(m_i, mb);
            const float alpha = exp2f(m_i - mnew);
#pragma unroll
            for (int kt = 0; kt < 8; kt++)
#pragma unroll
                for (int r = 0; r < 4; r++) {
                    const float p = exp2f(ST[kt][r] - mnew);
                    pv[kt][r] = (bf16r)p;
                    rs += p;
                }
            rs += __shfl_xor(rs, 16);
            rs += __shfl_xor(rs, 32);
            l_i = l_i * alpha + rs;
            m_i = mnew;
#pragma unroll
            for (int dt = 0; dt < 4; dt++)
#pragma unroll
                for (int r = 0; r < 4; r++) O[dt][r] *= alpha;
        }

        // ---- P^T -> Ps[q][key] via 8B vector writes (wave-private) ----
#pragma unroll
        for (int kt = 0; kt < 8; kt++) {
            const int phys = (kt * 2 + (qd >> 1)) ^ sw;  // 16B-chunk swizzle
            *(bf16x4*)&Ps[w][c][phys * 8 + (qd & 1) * 4] = pv[kt];
        }

        // ---- O^T += VT P^T (16x16x32) ----
#pragma unroll
        for (int ks = 0; ks < 4; ks++) {
            bf16x8 pf = *(const bf16x8*)&Ps[w][c][((ks * 4 + qd) ^ sw) * 8];
#pragma unroll
            for (int dt = 0; dt < 4; dt++) {
                bf16x8 vf = *(const bf16x8*)&VTs[cur][dt * 16 + c][((ks * 4 + qd) ^ sw) * 8];
                O[dt] = __builtin_amdgcn_mfma_f32_16x16x32_bf16(vf, pf, O[dt], 0, 0, 0);
            }
        }
        cur ^= 1;
    }

    // ---- epilogue: y[qrow][h*64 + d], 8B vector stores ----
    const float inv_l = 1.0f / l_i;
#pragma unroll
    for (int dt = 0; dt < 4; dt++) {
        bf16x4 ov;
#pragma unroll
        for (int r = 0; r < 4; r++) ov[r] = (bf16r)(O[dt][r] * inv_l);
        *(bf16x4*)(y + (size_t)qrow * C_DIM + h * 64 + dt * 16 + qd * 4) = ov;
    }
}

// ---------------------------------------------------------------------------
// launch.  Inputs f32, output f32.  ws peak = 56 MiB.
// ---------------------------------------------------------------------------
extern "C" void kernel_launch(void* const* d_in, const int* in_sizes, int n_in,
                              void* d_out, int out_size, void* d_ws, size_t ws_size,
                              hipStream_t stream) {
    const float* x        = (const float*)d_in[0];
    const float* attn_w   = (const float*)d_in[1];
    const float* ffn_w    = (const float*)d_in[2];
    const float* c_attn_w = (const float*)d_in[3];
    const float* c_proj_w = (const float*)d_in[4];
    const float* w1       = (const float*)d_in[5];
    const float* w2       = (const float*)d_in[6];
    const float* w3       = (const float*)d_in[7];
    float* xmid = (float*)d_out;

    char* ws = (char*)d_ws;
    bf16* cwA = (bf16*)(ws);
    bf16* cwP = (bf16*)(ws + MB(6));
    bf16* rms = (bf16*)(ws + MB(8));
    bf16* qkv = (bf16*)(ws + MB(16));
    bf16* VT  = (bf16*)(ws + MB(40));
    bf16* y   = (bf16*)(ws + MB(48));
    bf16* w1h = (bf16*)(ws + MB(16));
    bf16* w3h = (bf16*)(ws + MB(20));
    bf16* w2h = (bf16*)(ws + MB(24));
    bf16* h1h = (bf16*)(ws + MB(28));

    // 1. attention weights -> bf16
    cvt_w<<<512, 256, 0, stream>>>(c_attn_w, 0, (ushort4*)cwA, 3072 * 1024 / 4);
    cvt_w<<<512, 256, 0, stream>>>(c_proj_w, 0, (ushort4*)cwP, 1024 * 1024 / 4);
    // 2. rms1 = rmsnorm(x, attn_norm_w)
    rmsnorm_k<<<T_SEQ, 256, 0, stream>>>(x, attn_w, rms);
    // 3. qkv = rms1 @ c_attn^T   [4096, 3072]
    gemm128<0, 0><<<dim3(24, 32), 256, 0, stream>>>(rms, C_DIM, cwA, C_DIM, nullptr, qkv, 3072, 1024);
    // 4. VT (V transposed per head) + MFMA flash attention v5
    build_tr<<<dim3(64, 16), 256, 0, stream>>>(qkv, VT, 2 * C_DIM);
    attn_mfma<<<1024, 256, 0, stream>>>(qkv, VT, y);
    // 5. xmid = x + y @ c_proj^T   (f32, into d_out)
    gemm128<2, 1><<<dim3(8, 32), 256, 0, stream>>>(y, C_DIM, cwP, C_DIM, x, xmid, 1024, 1024);
    // 6. rms2 = rmsnorm(xmid, ffn_norm_w)
    rmsnorm_k<<<T_SEQ, 256, 0, stream>>>(xmid, ffn_w, rms);
    // 7. FFN in two Hf=2048 halves; w2-partials accumulate into xmid in place.
    for (int hh = 0; hh < 2; hh++) {
        cvt_w<<<512, 256, 0, stream>>>(w1, (size_t)hh * 2048 * 1024, (ushort4*)w1h, 2048 * 1024 / 4);
        gemm128<0, 0><<<dim3(16, 32), 256, 0, stream>>>(rms, C_DIM, w1h, C_DIM, nullptr, h1h, 2048, 1024);
        cvt_w<<<512, 256, 0, stream>>>(w3, (size_t)hh * 2048 * 1024, (ushort4*)w3h, 2048 * 1024 / 4);
        gemm128<3, 0><<<dim3(16, 32), 256, 0, stream>>>(rms, C_DIM, w3h, C_DIM, h1h, h1h, 2048, 1024);
        cvt_w2h<<<2048, 256, 0, stream>>>(w2, hh * 2048, (ushort4*)w2h);
        gemm128<2, 1><<<dim3(8, 32), 256, 0, stream>>>(h1h, 2048, w2h, 2048, xmid, xmid, 1024, 2048);
    }
}

// Round 5
// 531.492 us; speedup vs baseline: 1.1897x; 1.0893x over previous
//
#include <hip/hip_runtime.h>
#include <hip/hip_bf16.h>

typedef __hip_bfloat16 bf16;
typedef __bf16 bf16r;
typedef bf16r bf16x8 __attribute__((ext_vector_type(8)));
typedef bf16r bf16x4 __attribute__((ext_vector_type(4)));
typedef float f32x4 __attribute__((ext_vector_type(4)));

#define T_SEQ 4096
#define C_DIM 1024
#define LD_QKV 3072
#define MB(x) ((size_t)(x) << 20)
// 0.125 (1/sqrt(64)) * log2(e): softmax runs in exp2 domain
#define SCL 0.18033688011112042f

static __device__ __forceinline__ unsigned short f2bf(float f) {
    bf16 h = (bf16)f;
    return *reinterpret_cast<unsigned short*>(&h);
}

// ---------------------------------------------------------------------------
// f32 -> bf16 weight convert, contiguous slice
// ---------------------------------------------------------------------------
__global__ __launch_bounds__(256) void cvt_w(const float* __restrict__ src, size_t eoff,
                                             ushort4* __restrict__ dst, int n4) {
    int i = blockIdx.x * 256 + threadIdx.x;
    const int stride = gridDim.x * 256;
    const float4* s = (const float4*)(src + eoff);
    for (; i < n4; i += stride) {
        float4 v = s[i];
        ushort4 o;
        o.x = f2bf(v.x); o.y = f2bf(v.y); o.z = f2bf(v.z); o.w = f2bf(v.w);
        dst[i] = o;
    }
}

// ---------------------------------------------------------------------------
// w2 column-slice convert: src f32 [1024][4096], cols [coff, coff+2048)
// -> dst bf16 [1024][2048] (compacted, ld = 2048).
// ---------------------------------------------------------------------------
__global__ __launch_bounds__(256) void cvt_w2h(const float* __restrict__ src, int coff,
                                               ushort4* __restrict__ dst) {
    const int i = blockIdx.x * 256 + threadIdx.x;
    const int row = i >> 9;
    const int c4 = i & 511;
    float4 v = *(const float4*)(src + (size_t)row * 4096 + coff + c4 * 4);
    ushort4 o;
    o.x = f2bf(v.x); o.y = f2bf(v.y); o.z = f2bf(v.z); o.w = f2bf(v.w);
    dst[i] = o;
}

// ---------------------------------------------------------------------------
// RMSNorm: f32 in, f32 weight, bf16 out. One block per row of 1024.
// ---------------------------------------------------------------------------
__global__ __launch_bounds__(256) void rmsnorm_k(const float* __restrict__ x,
                                                 const float* __restrict__ w,
                                                 bf16* __restrict__ out) {
    const int row = blockIdx.x;
    const int tid = threadIdx.x;
    const float* xr = x + (size_t)row * C_DIM;
    float v[4];
    float ss = 0.f;
#pragma unroll
    for (int i = 0; i < 4; i++) { v[i] = xr[tid * 4 + i]; ss += v[i] * v[i]; }
#pragma unroll
    for (int off = 32; off; off >>= 1) ss += __shfl_xor(ss, off);
    __shared__ float red[4];
    if ((tid & 63) == 0) red[tid >> 6] = ss;
    __syncthreads();
    const float tot = red[0] + red[1] + red[2] + red[3];
    const float scale = rsqrtf(tot * (1.0f / C_DIM) + 1e-6f);
#pragma unroll
    for (int i = 0; i < 4; i++) {
        const int c = tid * 4 + i;
        out[(size_t)row * C_DIM + c] = (bf16)(v[i] * scale * w[c]);
    }
}

// ---------------------------------------------------------------------------
// m97-structure GEMM: out[M,N] = A[M,K](lda) @ B[N,K](ldb)^T (+ epilogue)
// (unchanged)
// ---------------------------------------------------------------------------
template <int RESID, int OUTF32>
__global__ __launch_bounds__(256) void gemm128(const bf16* __restrict__ A, int lda,
                                               const bf16* __restrict__ B, int ldb,
                                               const void* __restrict__ resid,
                                               void* __restrict__ out,
                                               int N, int K) {
    __shared__ __align__(16) bf16r As[128 * 32];
    __shared__ __align__(16) bf16r Bs[128 * 32];
    const int tid = threadIdx.x;
    const int w = tid >> 6, lane = tid & 63;
    const int c = lane & 15, qd = lane >> 4;
    const int wm = w >> 1, wn = w & 1;
    const int mbase = blockIdx.y * 128;
    const int nbase = blockIdx.x * 128;

    const int srow = lane >> 2, schk = lane & 3;
    const bf16* gA = A + (size_t)(mbase + w * 32 + srow) * lda + schk * 8;
    const bf16* gB = B + (size_t)(nbase + w * 32 + srow) * ldb + schk * 8;

    f32x4 acc[4][4] = {};

    for (int k0 = 0; k0 < K; k0 += 32) {
        __syncthreads();
#pragma unroll
        for (int s = 0; s < 2; s++) {
            __builtin_amdgcn_global_load_lds(
                (const __attribute__((address_space(1))) void*)(gA + (size_t)(s * 16) * lda + k0),
                (__attribute__((address_space(3))) void*)&As[(w * 32 + s * 16) * 32], 16, 0, 0);
            __builtin_amdgcn_global_load_lds(
                (const __attribute__((address_space(1))) void*)(gB + (size_t)(s * 16) * ldb + k0),
                (__attribute__((address_space(3))) void*)&Bs[(w * 32 + s * 16) * 32], 16, 0, 0);
        }
        __syncthreads();

        bf16x8 a[4], b[4];
#pragma unroll
        for (int i = 0; i < 4; i++)
            a[i] = *(const bf16x8*)&As[(wm * 64 + i * 16 + c) * 32 + qd * 8];
#pragma unroll
        for (int j = 0; j < 4; j++)
            b[j] = *(const bf16x8*)&Bs[(wn * 64 + j * 16 + c) * 32 + qd * 8];
#pragma unroll
        for (int i = 0; i < 4; i++)
#pragma unroll
            for (int j = 0; j < 4; j++)
                acc[i][j] = __builtin_amdgcn_mfma_f32_16x16x32_bf16(a[i], b[j], acc[i][j], 0, 0, 0);
    }

#pragma unroll
    for (int i = 0; i < 4; i++) {
#pragma unroll
        for (int j = 0; j < 4; j++) {
            const int col = nbase + wn * 64 + j * 16 + c;
#pragma unroll
            for (int reg = 0; reg < 4; reg++) {
                const int row = mbase + wm * 64 + i * 16 + qd * 4 + reg;
                const size_t idx = (size_t)row * N + col;
                float v = acc[i][j][reg];
                if (RESID == 2) v += ((const float*)resid)[idx];
                if (RESID == 3) {
                    const float a1 = (float)((const bf16*)resid)[idx];
                    v = (a1 / (1.0f + __expf(-a1))) * v;
                }
                if (OUTF32)
                    ((float*)out)[idx] = v;
                else
                    ((bf16*)out)[idx] = (bf16)v;
            }
        }
    }
}

// ---------------------------------------------------------------------------
// Transpose a qkv section to [h][d][t]
// ---------------------------------------------------------------------------
__global__ __launch_bounds__(256) void build_tr(const bf16* __restrict__ qkv,
                                                bf16* __restrict__ dst, int soff) {
    const int h = blockIdx.y;
    const int tb = blockIdx.x;
    __shared__ bf16 tile[64][65];
    const int tx = threadIdx.x & 63;
    const int ty = threadIdx.x >> 6;
    for (int rr = ty; rr < 64; rr += 4)
        tile[rr][tx] = qkv[(size_t)(tb * 64 + rr) * LD_QKV + soff + h * 64 + tx];
    __syncthreads();
    for (int rr = ty; rr < 64; rr += 4)
        dst[((size_t)h * 64 + rr) * T_SEQ + tb * 64 + tx] = tile[tx][rr];
}

// ---------------------------------------------------------------------------
// zero the 8 per-queue work counters (64B-padded: one cache line each, so
// cross-XCD atomics don't bounce a shared line)
// ---------------------------------------------------------------------------
#define CTR_STRIDE 16  // ints; 64 B
__global__ void zero_ctr(int* p) { if (threadIdx.x < 8 * CTR_STRIDE) p[threadIdx.x] = 0; }

// ---------------------------------------------------------------------------
// MFMA flash attention v6 = v2 chunk body (proven fastest: serial staging,
// 48 KB LDS, 3 blocks/CU) + exp2-domain softmax + defer-max + PERSISTENT
// BLOCKS with LPT work queue.
//
// Round-3 finding: the bottleneck was never per-chunk latency, it was LOAD
// IMBALANCE.  With block id = qt*16+h and stride-256 id->CU assignment, the
// old heavy/light qb pairing put qb={63,55,47,39} (104 chunks) on some CUs
// and qb={0,8,16,24} (28 chunks) on others -> wall ~ heavy-CU makespan,
// ~14% avg occupancy (light CUs drain and idle).  Every per-chunk tweak
// under-delivered because stragglers set the critical path.
//
// v6: 768 persistent blocks (exactly 3/CU at 48 KB), 8 atomic work queues
// indexed by blockIdx&7 (matches the empirical id%8->XCD mapping, keeping
// each queue's K/V at 2 heads = 2 MB = L2-resident per XCD; if the mapping
// assumption is wrong only L2 locality degrades, never correctness).
// Queue qi serves heads {qi, qi+8}; item j -> qb = 63-(j>>1) (largest-first
// LPT), h = qi + 8*(j&1).  Makespan per queue -> ~32 chunk-times (bounded by
// the single heaviest tile), tail filled by 1-5-chunk items.
// Termination: counter is monotone, every block exits after <=128 grabs;
// no inter-block waits, so no co-residency requirement.
//
// Only the last (diagonal) 128-key chunk needs causal masking (for kb<nkb-1
// max staged key = kb*128+127 < qb*64 = min q of the tile).
// ---------------------------------------------------------------------------
__global__ __launch_bounds__(256) void attn_mfma(const bf16* __restrict__ qkv,
                                                 const bf16* __restrict__ VT,
                                                 bf16* __restrict__ y,
                                                 int* __restrict__ ctrs) {
    __shared__ __align__(16) bf16r Ks[128][64];    // keys x d
    __shared__ __align__(16) bf16r VTs[64][128];   // d x keys
    __shared__ __align__(16) bf16r Ps[4][16][128]; // per-wave q x keys
    __shared__ int s_wi;

    const int tid  = threadIdx.x;
    const int w    = tid >> 6;
    const int lane = tid & 63;
    const int c    = lane & 15;
    const int qd   = lane >> 4;
    const int sw   = c & 7;            // xor swizzle key for frag reads
    const int qi   = blockIdx.x & 7;   // queue = presumed XCD
    int* ctr = ctrs + qi * CTR_STRIDE;

    while (true) {
        __syncthreads();               // LDS + s_wi safe to reuse
        if (tid == 0) s_wi = atomicAdd(ctr, 1);
        __syncthreads();
        const int j = s_wi;
        if (j >= 128) break;           // queue drained (uniform exit)

        const int h    = qi + 8 * (j & 1);      // heads {qi, qi+8}
        const int qb   = 63 - (j >> 1);         // largest-first (LPT)
        const int qrow = qb * 64 + w * 16 + c;

        // Q B-frags: lane holds Q[qrow][ks*32 + qd*8 + jj]
        bf16x8 qf[2];
        {
            const bf16* qp = qkv + (size_t)qrow * LD_QKV + h * 64;
            qf[0] = *(const bf16x8*)(qp + qd * 8);
            qf[1] = *(const bf16x8*)(qp + 32 + qd * 8);
        }

        f32x4 O[4] = {};               // O^T: D[row=d=dt*16+qd*4+r][col=q=c]
        float m_i = -1e30f, l_i = 0.f; // m_i in log2 domain
        const int nkb = (qb >> 1) + 1; // 128-key chunks

        for (int kb = 0; kb < nkb; kb++) {
            __syncthreads();           // prior iteration's LDS reads done
#pragma unroll
            for (int ii = 0; ii < 4; ii++) {
                const int i = ii * 256 + tid;
                const int kr = i >> 3, ch = i & 7;    // K: 128 rows x 8 chunks
                *(bf16x8*)&Ks[kr][(ch ^ (kr & 7)) * 8] =
                    *(const bf16x8*)(qkv + (size_t)(kb * 128 + kr) * LD_QKV + C_DIM + h * 64 + ch * 8);
                const int vr = i >> 4, vch = i & 15;  // VT: 64 rows x 16 chunks
                *(bf16x8*)&VTs[vr][(vch ^ (vr & 7)) * 8] =
                    *(const bf16x8*)(VT + ((size_t)h * 64 + vr) * T_SEQ + kb * 128 + vch * 8);
            }
            __syncthreads();

            // ---- S^T = K Q^T : rows = keys (kt*16+qd*4+r), cols = q (c) ----
            f32x4 ST[8];
#pragma unroll
            for (int kt = 0; kt < 8; kt++) {
                f32x4 z = {};
#pragma unroll
                for (int ks = 0; ks < 2; ks++) {
                    bf16x8 kf = *(const bf16x8*)&Ks[kt * 16 + c][((ks * 4 + qd) ^ sw) * 8];
                    z = __builtin_amdgcn_mfma_f32_16x16x32_bf16(kf, qf[ks], z, 0, 0, 0);
                }
                ST[kt] = z;
            }

            // ---- scale to log2 domain (+ causal mask on diagonal chunk) ----
            if (kb == nkb - 1) {
#pragma unroll
                for (int kt = 0; kt < 8; kt++)
#pragma unroll
                    for (int r = 0; r < 4; r++) {
                        float s = ST[kt][r] * SCL;
                        if (kb * 128 + kt * 16 + qd * 4 + r > qrow) s = -1e30f;
                        ST[kt][r] = s;
                    }
            } else {
#pragma unroll
                for (int kt = 0; kt < 8; kt++)
#pragma unroll
                    for (int r = 0; r < 4; r++) ST[kt][r] *= SCL;
            }

            // ---- online softmax (exp2 domain), per-lane scalar stats ----
            float mb = -1e30f;
#pragma unroll
            for (int kt = 0; kt < 8; kt++)
#pragma unroll
                for (int r = 0; r < 4; r++) mb = fmaxf(mb, ST[kt][r]);
            mb = fmaxf(mb, __shfl_xor(mb, 16));
            mb = fmaxf(mb, __shfl_xor(mb, 32));

            bf16x4 pv[8];
            float rs = 0.f;
            if (__all(mb - m_i <= 8.0f)) {
                // defer-max: keep m_i, skip alpha-rescale; P bounded by 2^8
#pragma unroll
                for (int kt = 0; kt < 8; kt++)
#pragma unroll
                    for (int r = 0; r < 4; r++) {
                        const float p = exp2f(ST[kt][r] - m_i);
                        pv[kt][r] = (bf16r)p;
                        rs += p;
                    }
                rs += __shfl_xor(rs, 16);
                rs += __shfl_xor(rs, 32);
                l_i += rs;
            } else {
                const float mnew = fmaxf(m_i, mb);
                const float alpha = exp2f(m_i - mnew);
#pragma unroll
                for (int kt = 0; kt < 8; kt++)
#pragma unroll
                    for (int r = 0; r < 4; r++) {
                        const float p = exp2f(ST[kt][r] - mnew);
                        pv[kt][r] = (bf16r)p;
                        rs += p;
                    }
                rs += __shfl_xor(rs, 16);
                rs += __shfl_xor(rs, 32);
                l_i = l_i * alpha + rs;
                m_i = mnew;
#pragma unroll
                for (int dt = 0; dt < 4; dt++)
#pragma unroll
                    for (int r = 0; r < 4; r++) O[dt][r] *= alpha;
            }

            // ---- P^T -> Ps[q][key] via 8B vector writes (wave-private) ----
#pragma unroll
            for (int kt = 0; kt < 8; kt++) {
                const int phys = (kt * 2 + (qd >> 1)) ^ sw;  // 16B-chunk swizzle
                *(bf16x4*)&Ps[w][c][phys * 8 + (qd & 1) * 4] = pv[kt];
            }

            // ---- O^T += VT P^T (16x16x32) ----
#pragma unroll
            for (int ks = 0; ks < 4; ks++) {
                bf16x8 pf = *(const bf16x8*)&Ps[w][c][((ks * 4 + qd) ^ sw) * 8];
#pragma unroll
                for (int dt = 0; dt < 4; dt++) {
                    bf16x8 vf = *(const bf16x8*)&VTs[dt * 16 + c][((ks * 4 + qd) ^ sw) * 8];
                    O[dt] = __builtin_amdgcn_mfma_f32_16x16x32_bf16(vf, pf, O[dt], 0, 0, 0);
                }
            }
        }

        // ---- epilogue: y[qrow][h*64 + d], 8B vector stores ----
        const float inv_l = 1.0f / l_i;
#pragma unroll
        for (int dt = 0; dt < 4; dt++) {
            bf16x4 ov;
#pragma unroll
            for (int r = 0; r < 4; r++) ov[r] = (bf16r)(O[dt][r] * inv_l);
            *(bf16x4*)(y + (size_t)qrow * C_DIM + h * 64 + dt * 16 + qd * 4) = ov;
        }
    }
}

// ---------------------------------------------------------------------------
// launch.  Inputs f32, output f32.  ws peak = 56 MiB.
// ---------------------------------------------------------------------------
extern "C" void kernel_launch(void* const* d_in, const int* in_sizes, int n_in,
                              void* d_out, int out_size, void* d_ws, size_t ws_size,
                              hipStream_t stream) {
    const float* x        = (const float*)d_in[0];
    const float* attn_w   = (const float*)d_in[1];
    const float* ffn_w    = (const float*)d_in[2];
    const float* c_attn_w = (const float*)d_in[3];
    const float* c_proj_w = (const float*)d_in[4];
    const float* w1       = (const float*)d_in[5];
    const float* w2       = (const float*)d_in[6];
    const float* w3       = (const float*)d_in[7];
    float* xmid = (float*)d_out;

    char* ws = (char*)d_ws;
    bf16* cwA = (bf16*)(ws);
    bf16* cwP = (bf16*)(ws + MB(6));
    bf16* rms = (bf16*)(ws + MB(8));
    bf16* qkv = (bf16*)(ws + MB(16));
    bf16* VT  = (bf16*)(ws + MB(40));
    bf16* y   = (bf16*)(ws + MB(48));
    bf16* w1h = (bf16*)(ws + MB(16));
    bf16* w3h = (bf16*)(ws + MB(20));
    bf16* w2h = (bf16*)(ws + MB(24));
    bf16* h1h = (bf16*)(ws + MB(28));
    // work-queue counters live in the rms region: written AFTER step 3 has
    // consumed rms1, overwritten again only at step 6 (stream-ordered).
    int* ctrs = (int*)(ws + MB(8));

    // 1. attention weights -> bf16
    cvt_w<<<512, 256, 0, stream>>>(c_attn_w, 0, (ushort4*)cwA, 3072 * 1024 / 4);
    cvt_w<<<512, 256, 0, stream>>>(c_proj_w, 0, (ushort4*)cwP, 1024 * 1024 / 4);
    // 2. rms1 = rmsnorm(x, attn_norm_w)
    rmsnorm_k<<<T_SEQ, 256, 0, stream>>>(x, attn_w, rms);
    // 3. qkv = rms1 @ c_attn^T   [4096, 3072]
    gemm128<0, 0><<<dim3(24, 32), 256, 0, stream>>>(rms, C_DIM, cwA, C_DIM, nullptr, qkv, 3072, 1024);
    // 4. VT (V transposed per head) + persistent-block flash attention v6
    build_tr<<<dim3(64, 16), 256, 0, stream>>>(qkv, VT, 2 * C_DIM);
    zero_ctr<<<1, 128, 0, stream>>>(ctrs);
    attn_mfma<<<768, 256, 0, stream>>>(qkv, VT, y, ctrs);
    // 5. xmid = x + y @ c_proj^T   (f32, into d_out)
    gemm128<2, 1><<<dim3(8, 32), 256, 0, stream>>>(y, C_DIM, cwP, C_DIM, x, xmid, 1024, 1024);
    // 6. rms2 = rmsnorm(xmid, ffn_norm_w)
    rmsnorm_k<<<T_SEQ, 256, 0, stream>>>(xmid, ffn_w, rms);
    // 7. FFN in two Hf=2048 halves; w2-partials accumulate into xmid in place.
    for (int hh = 0; hh < 2; hh++) {
        cvt_w<<<512, 256, 0, stream>>>(w1, (size_t)hh * 2048 * 1024, (ushort4*)w1h, 2048 * 1024 / 4);
        gemm128<0, 0><<<dim3(16, 32), 256, 0, stream>>>(rms, C_DIM, w1h, C_DIM, nullptr, h1h, 2048, 1024);
        cvt_w<<<512, 256, 0, stream>>>(w3, (size_t)hh * 2048 * 1024, (ushort4*)w3h, 2048 * 1024 / 4);
        gemm128<3, 0><<<dim3(16, 32), 256, 0, stream>>>(rms, C_DIM, w3h, C_DIM, h1h, h1h, 2048, 1024);
        cvt_w2h<<<2048, 256, 0, stream>>>(w2, hh * 2048, (ushort4*)w2h);
        gemm128<2, 1><<<dim3(8, 32), 256, 0, stream>>>(h1h, 2048, w2h, 2048, xmid, xmid, 1024, 2048);
    }
}

// Round 6
// 508.726 us; speedup vs baseline: 1.2429x; 1.0448x over previous
//
#include <hip/hip_runtime.h>
#include <hip/hip_bf16.h>

typedef __hip_bfloat16 bf16;
typedef __bf16 bf16r;
typedef bf16r bf16x8 __attribute__((ext_vector_type(8)));
typedef bf16r bf16x4 __attribute__((ext_vector_type(4)));
typedef float f32x4 __attribute__((ext_vector_type(4)));

#define T_SEQ 4096
#define C_DIM 1024
#define LD_QKV 3072
#define MB(x) ((size_t)(x) << 20)
// 0.125 (1/sqrt(64)) * log2(e): softmax runs in exp2 domain.  Folded into the
// Q-projection weights at cvt time, so QK^T lands already log2-scaled.
#define SCL 0.18033688011112042f

static __device__ __forceinline__ unsigned short f2bf(float f) {
    bf16 h = (bf16)f;
    return *reinterpret_cast<unsigned short*>(&h);
}

// ---------------------------------------------------------------------------
// f32 -> bf16 weight convert, contiguous slice; first n4scl float4's are
// multiplied by scl (used to fold the attention scale into Q-proj rows).
// ---------------------------------------------------------------------------
__global__ __launch_bounds__(256) void cvt_w(const float* __restrict__ src, size_t eoff,
                                             ushort4* __restrict__ dst, int n4,
                                             int n4scl, float scl) {
    int i = blockIdx.x * 256 + threadIdx.x;
    const int stride = gridDim.x * 256;
    const float4* s = (const float4*)(src + eoff);
    for (; i < n4; i += stride) {
        float4 v = s[i];
        const float m = (i < n4scl) ? scl : 1.0f;
        ushort4 o;
        o.x = f2bf(v.x * m); o.y = f2bf(v.y * m); o.z = f2bf(v.z * m); o.w = f2bf(v.w * m);
        dst[i] = o;
    }
}

// ---------------------------------------------------------------------------
// w2 column-slice convert: src f32 [1024][4096], cols [coff, coff+2048)
// -> dst bf16 [1024][2048] (compacted, ld = 2048).
// ---------------------------------------------------------------------------
__global__ __launch_bounds__(256) void cvt_w2h(const float* __restrict__ src, int coff,
                                               ushort4* __restrict__ dst) {
    const int i = blockIdx.x * 256 + threadIdx.x;
    const int row = i >> 9;
    const int c4 = i & 511;
    float4 v = *(const float4*)(src + (size_t)row * 4096 + coff + c4 * 4);
    ushort4 o;
    o.x = f2bf(v.x); o.y = f2bf(v.y); o.z = f2bf(v.z); o.w = f2bf(v.w);
    dst[i] = o;
}

// ---------------------------------------------------------------------------
// f32 grid-stride copy (xmid = x prefill for the atomic split-K epilogues)
// ---------------------------------------------------------------------------
__global__ __launch_bounds__(256) void copy_f32(const float4* __restrict__ src,
                                                float4* __restrict__ dst, int n4) {
    int i = blockIdx.x * 256 + threadIdx.x;
    const int stride = gridDim.x * 256;
    for (; i < n4; i += stride) dst[i] = src[i];
}

// ---------------------------------------------------------------------------
// RMSNorm: f32 in, f32 weight, bf16 out. One block per row of 1024.
// ---------------------------------------------------------------------------
__global__ __launch_bounds__(256) void rmsnorm_k(const float* __restrict__ x,
                                                 const float* __restrict__ w,
                                                 bf16* __restrict__ out) {
    const int row = blockIdx.x;
    const int tid = threadIdx.x;
    const float* xr = x + (size_t)row * C_DIM;
    float v[4];
    float ss = 0.f;
#pragma unroll
    for (int i = 0; i < 4; i++) { v[i] = xr[tid * 4 + i]; ss += v[i] * v[i]; }
#pragma unroll
    for (int off = 32; off; off >>= 1) ss += __shfl_xor(ss, off);
    __shared__ float red[4];
    if ((tid & 63) == 0) red[tid >> 6] = ss;
    __syncthreads();
    const float tot = red[0] + red[1] + red[2] + red[3];
    const float scale = rsqrtf(tot * (1.0f / C_DIM) + 1e-6f);
#pragma unroll
    for (int i = 0; i < 4; i++) {
        const int c = tid * 4 + i;
        out[(size_t)row * C_DIM + c] = (bf16)(v[i] * scale * w[c]);
    }
}

// ---------------------------------------------------------------------------
// m97-structure GEMM: out[M,N] = A[M,K](lda) @ B[N,K](ldb)^T (+ epilogue).
// K is the PER-SLICE reduction length; blockIdx.z selects the K-slice
// (koff = z*K), enabling split-K for grid-starved shapes (N=1024 -> only
// 256 blocks = 1 block/CU; z=2 doubles residency).  RESID==4: f32 atomicAdd
// epilogue (requires out prefilled; slices race-free via atomics).
// ---------------------------------------------------------------------------
template <int RESID, int OUTF32>
__global__ __launch_bounds__(256) void gemm128(const bf16* __restrict__ A, int lda,
                                               const bf16* __restrict__ B, int ldb,
                                               const void* __restrict__ resid,
                                               void* __restrict__ out,
                                               int N, int K) {
    __shared__ __align__(16) bf16r As[128 * 32];
    __shared__ __align__(16) bf16r Bs[128 * 32];
    const int tid = threadIdx.x;
    const int w = tid >> 6, lane = tid & 63;
    const int c = lane & 15, qd = lane >> 4;
    const int wm = w >> 1, wn = w & 1;
    const int mbase = blockIdx.y * 128;
    const int nbase = blockIdx.x * 128;
    const size_t koff = (size_t)blockIdx.z * K;

    const int srow = lane >> 2, schk = lane & 3;
    const bf16* gA = A + (size_t)(mbase + w * 32 + srow) * lda + schk * 8 + koff;
    const bf16* gB = B + (size_t)(nbase + w * 32 + srow) * ldb + schk * 8 + koff;

    f32x4 acc[4][4] = {};

    for (int k0 = 0; k0 < K; k0 += 32) {
        __syncthreads();
#pragma unroll
        for (int s = 0; s < 2; s++) {
            __builtin_amdgcn_global_load_lds(
                (const __attribute__((address_space(1))) void*)(gA + (size_t)(s * 16) * lda + k0),
                (__attribute__((address_space(3))) void*)&As[(w * 32 + s * 16) * 32], 16, 0, 0);
            __builtin_amdgcn_global_load_lds(
                (const __attribute__((address_space(1))) void*)(gB + (size_t)(s * 16) * ldb + k0),
                (__attribute__((address_space(3))) void*)&Bs[(w * 32 + s * 16) * 32], 16, 0, 0);
        }
        __syncthreads();

        bf16x8 a[4], b[4];
#pragma unroll
        for (int i = 0; i < 4; i++)
            a[i] = *(const bf16x8*)&As[(wm * 64 + i * 16 + c) * 32 + qd * 8];
#pragma unroll
        for (int j = 0; j < 4; j++)
            b[j] = *(const bf16x8*)&Bs[(wn * 64 + j * 16 + c) * 32 + qd * 8];
#pragma unroll
        for (int i = 0; i < 4; i++)
#pragma unroll
            for (int j = 0; j < 4; j++)
                acc[i][j] = __builtin_amdgcn_mfma_f32_16x16x32_bf16(a[i], b[j], acc[i][j], 0, 0, 0);
    }

#pragma unroll
    for (int i = 0; i < 4; i++) {
#pragma unroll
        for (int j = 0; j < 4; j++) {
            const int col = nbase + wn * 64 + j * 16 + c;
#pragma unroll
            for (int reg = 0; reg < 4; reg++) {
                const int row = mbase + wm * 64 + i * 16 + qd * 4 + reg;
                const size_t idx = (size_t)row * N + col;
                float v = acc[i][j][reg];
                if (RESID == 2) v += ((const float*)resid)[idx];
                if (RESID == 3) {
                    const float a1 = (float)((const bf16*)resid)[idx];
                    v = (a1 / (1.0f + __expf(-a1))) * v;
                }
                if (RESID == 4) {
                    atomicAdd(&((float*)out)[idx], v);
                } else if (OUTF32) {
                    ((float*)out)[idx] = v;
                } else {
                    ((bf16*)out)[idx] = (bf16)v;
                }
            }
        }
    }
}

// ---------------------------------------------------------------------------
// Merged w1/w3 GEMM: h = silu(A@B1^T) * (A@B3^T), bf16 out [M, N].
// One A-staging feeds both B matrices (32 MFMA per K-step); the h1
// bf16 round-trip and the separate silu pass are eliminated, and silu is
// computed from f32 accumulators (closer to the f32 reference).
// ---------------------------------------------------------------------------
__global__ __launch_bounds__(256, 2) void gemm_w13(const bf16* __restrict__ A,
                                                   const bf16* __restrict__ B1,
                                                   const bf16* __restrict__ B3,
                                                   bf16* __restrict__ out,
                                                   int N, int K) {
    __shared__ __align__(16) bf16r As[128 * 32];
    __shared__ __align__(16) bf16r B1s[128 * 32];
    __shared__ __align__(16) bf16r B3s[128 * 32];
    const int tid = threadIdx.x;
    const int w = tid >> 6, lane = tid & 63;
    const int c = lane & 15, qd = lane >> 4;
    const int wm = w >> 1, wn = w & 1;
    const int mbase = blockIdx.y * 128;
    const int nbase = blockIdx.x * 128;

    const int srow = lane >> 2, schk = lane & 3;
    const bf16* gA = A + (size_t)(mbase + w * 32 + srow) * K + schk * 8;
    const bf16* gB1 = B1 + (size_t)(nbase + w * 32 + srow) * K + schk * 8;
    const bf16* gB3 = B3 + (size_t)(nbase + w * 32 + srow) * K + schk * 8;

    f32x4 acc1[4][4] = {};
    f32x4 acc3[4][4] = {};

    for (int k0 = 0; k0 < K; k0 += 32) {
        __syncthreads();
#pragma unroll
        for (int s = 0; s < 2; s++) {
            __builtin_amdgcn_global_load_lds(
                (const __attribute__((address_space(1))) void*)(gA + (size_t)(s * 16) * K + k0),
                (__attribute__((address_space(3))) void*)&As[(w * 32 + s * 16) * 32], 16, 0, 0);
            __builtin_amdgcn_global_load_lds(
                (const __attribute__((address_space(1))) void*)(gB1 + (size_t)(s * 16) * K + k0),
                (__attribute__((address_space(3))) void*)&B1s[(w * 32 + s * 16) * 32], 16, 0, 0);
            __builtin_amdgcn_global_load_lds(
                (const __attribute__((address_space(1))) void*)(gB3 + (size_t)(s * 16) * K + k0),
                (__attribute__((address_space(3))) void*)&B3s[(w * 32 + s * 16) * 32], 16, 0, 0);
        }
        __syncthreads();

        bf16x8 a[4], b1[4], b3[4];
#pragma unroll
        for (int i = 0; i < 4; i++)
            a[i] = *(const bf16x8*)&As[(wm * 64 + i * 16 + c) * 32 + qd * 8];
#pragma unroll
        for (int j = 0; j < 4; j++) {
            b1[j] = *(const bf16x8*)&B1s[(wn * 64 + j * 16 + c) * 32 + qd * 8];
            b3[j] = *(const bf16x8*)&B3s[(wn * 64 + j * 16 + c) * 32 + qd * 8];
        }
#pragma unroll
        for (int i = 0; i < 4; i++)
#pragma unroll
            for (int j = 0; j < 4; j++) {
                acc1[i][j] = __builtin_amdgcn_mfma_f32_16x16x32_bf16(a[i], b1[j], acc1[i][j], 0, 0, 0);
                acc3[i][j] = __builtin_amdgcn_mfma_f32_16x16x32_bf16(a[i], b3[j], acc3[i][j], 0, 0, 0);
            }
    }

#pragma unroll
    for (int i = 0; i < 4; i++) {
#pragma unroll
        for (int j = 0; j < 4; j++) {
            const int col = nbase + wn * 64 + j * 16 + c;
#pragma unroll
            for (int reg = 0; reg < 4; reg++) {
                const int row = mbase + wm * 64 + i * 16 + qd * 4 + reg;
                const float a1 = acc1[i][j][reg];
                const float h = (a1 / (1.0f + __expf(-a1))) * acc3[i][j][reg];
                out[(size_t)row * N + col] = (bf16)h;
            }
        }
    }
}

// ---------------------------------------------------------------------------
// Transpose a qkv section to [h][d][t]
// ---------------------------------------------------------------------------
__global__ __launch_bounds__(256) void build_tr(const bf16* __restrict__ qkv,
                                                bf16* __restrict__ dst, int soff) {
    const int h = blockIdx.y;
    const int tb = blockIdx.x;
    __shared__ bf16 tile[64][65];
    const int tx = threadIdx.x & 63;
    const int ty = threadIdx.x >> 6;
    for (int rr = ty; rr < 64; rr += 4)
        tile[rr][tx] = qkv[(size_t)(tb * 64 + rr) * LD_QKV + soff + h * 64 + tx];
    __syncthreads();
    for (int rr = ty; rr < 64; rr += 4)
        dst[((size_t)h * 64 + rr) * T_SEQ + tb * 64 + tx] = tile[tx][rr];
}

// ---------------------------------------------------------------------------
// zero the 8 per-queue work counters (64B-padded: one cache line each)
// ---------------------------------------------------------------------------
#define CTR_STRIDE 16  // ints; 64 B
__global__ void zero_ctr(int* p) { if (threadIdx.x < 8 * CTR_STRIDE) p[threadIdx.x] = 0; }

// ---------------------------------------------------------------------------
// MFMA flash attention v7 = v6 (persistent blocks + 8 LPT work queues,
// proven -21%) with the softmax scale pre-folded into the Q weights:
// QK^T emerges already in log2 domain, so the per-chunk 32-mul scale pass
// is gone and the diagonal chunk only applies the causal mask.
// ---------------------------------------------------------------------------
__global__ __launch_bounds__(256) void attn_mfma(const bf16* __restrict__ qkv,
                                                 const bf16* __restrict__ VT,
                                                 bf16* __restrict__ y,
                                                 int* __restrict__ ctrs) {
    __shared__ __align__(16) bf16r Ks[128][64];    // keys x d
    __shared__ __align__(16) bf16r VTs[64][128];   // d x keys
    __shared__ __align__(16) bf16r Ps[4][16][128]; // per-wave q x keys
    __shared__ int s_wi;

    const int tid  = threadIdx.x;
    const int w    = tid >> 6;
    const int lane = tid & 63;
    const int c    = lane & 15;
    const int qd   = lane >> 4;
    const int sw   = c & 7;            // xor swizzle key for frag reads
    const int qi   = blockIdx.x & 7;   // queue = presumed XCD
    int* ctr = ctrs + qi * CTR_STRIDE;

    while (true) {
        __syncthreads();               // LDS + s_wi safe to reuse
        if (tid == 0) s_wi = atomicAdd(ctr, 1);
        __syncthreads();
        const int j = s_wi;
        if (j >= 128) break;           // queue drained (uniform exit)

        const int h    = qi + 8 * (j & 1);      // heads {qi, qi+8}
        const int qb   = 63 - (j >> 1);         // largest-first (LPT)
        const int qrow = qb * 64 + w * 16 + c;

        // Q B-frags: lane holds Q[qrow][ks*32 + qd*8 + jj]  (pre-scaled by SCL)
        bf16x8 qf[2];
        {
            const bf16* qp = qkv + (size_t)qrow * LD_QKV + h * 64;
            qf[0] = *(const bf16x8*)(qp + qd * 8);
            qf[1] = *(const bf16x8*)(qp + 32 + qd * 8);
        }

        f32x4 O[4] = {};               // O^T: D[row=d=dt*16+qd*4+r][col=q=c]
        float m_i = -1e30f, l_i = 0.f; // m_i in log2 domain
        const int nkb = (qb >> 1) + 1; // 128-key chunks

        for (int kb = 0; kb < nkb; kb++) {
            __syncthreads();           // prior iteration's LDS reads done
#pragma unroll
            for (int ii = 0; ii < 4; ii++) {
                const int i = ii * 256 + tid;
                const int kr = i >> 3, ch = i & 7;    // K: 128 rows x 8 chunks
                *(bf16x8*)&Ks[kr][(ch ^ (kr & 7)) * 8] =
                    *(const bf16x8*)(qkv + (size_t)(kb * 128 + kr) * LD_QKV + C_DIM + h * 64 + ch * 8);
                const int vr = i >> 4, vch = i & 15;  // VT: 64 rows x 16 chunks
                *(bf16x8*)&VTs[vr][(vch ^ (vr & 7)) * 8] =
                    *(const bf16x8*)(VT + ((size_t)h * 64 + vr) * T_SEQ + kb * 128 + vch * 8);
            }
            __syncthreads();

            // ---- S^T = K Q^T : rows = keys (kt*16+qd*4+r), cols = q (c) ----
            f32x4 ST[8];
#pragma unroll
            for (int kt = 0; kt < 8; kt++) {
                f32x4 z = {};
#pragma unroll
                for (int ks = 0; ks < 2; ks++) {
                    bf16x8 kf = *(const bf16x8*)&Ks[kt * 16 + c][((ks * 4 + qd) ^ sw) * 8];
                    z = __builtin_amdgcn_mfma_f32_16x16x32_bf16(kf, qf[ks], z, 0, 0, 0);
                }
                ST[kt] = z;
            }

            // ---- causal mask on the diagonal chunk only ----
            if (kb == nkb - 1) {
#pragma unroll
                for (int kt = 0; kt < 8; kt++)
#pragma unroll
                    for (int r = 0; r < 4; r++)
                        if (kb * 128 + kt * 16 + qd * 4 + r > qrow) ST[kt][r] = -1e30f;
            }

            // ---- online softmax (exp2 domain), per-lane scalar stats ----
            float mb = -1e30f;
#pragma unroll
            for (int kt = 0; kt < 8; kt++)
#pragma unroll
                for (int r = 0; r < 4; r++) mb = fmaxf(mb, ST[kt][r]);
            mb = fmaxf(mb, __shfl_xor(mb, 16));
            mb = fmaxf(mb, __shfl_xor(mb, 32));

            bf16x4 pv[8];
            float rs = 0.f;
            if (__all(mb - m_i <= 8.0f)) {
                // defer-max: keep m_i, skip alpha-rescale; P bounded by 2^8
#pragma unroll
                for (int kt = 0; kt < 8; kt++)
#pragma unroll
                    for (int r = 0; r < 4; r++) {
                        const float p = exp2f(ST[kt][r] - m_i);
                        pv[kt][r] = (bf16r)p;
                        rs += p;
                    }
                rs += __shfl_xor(rs, 16);
                rs += __shfl_xor(rs, 32);
                l_i += rs;
            } else {
                const float mnew = fmaxf(m_i, mb);
                const float alpha = exp2f(m_i - mnew);
#pragma unroll
                for (int kt = 0; kt < 8; kt++)
#pragma unroll
                    for (int r = 0; r < 4; r++) {
                        const float p = exp2f(ST[kt][r] - mnew);
                        pv[kt][r] = (bf16r)p;
                        rs += p;
                    }
                rs += __shfl_xor(rs, 16);
                rs += __shfl_xor(rs, 32);
                l_i = l_i * alpha + rs;
                m_i = mnew;
#pragma unroll
                for (int dt = 0; dt < 4; dt++)
#pragma unroll
                    for (int r = 0; r < 4; r++) O[dt][r] *= alpha;
            }

            // ---- P^T -> Ps[q][key] via 8B vector writes (wave-private) ----
#pragma unroll
            for (int kt = 0; kt < 8; kt++) {
                const int phys = (kt * 2 + (qd >> 1)) ^ sw;  // 16B-chunk swizzle
                *(bf16x4*)&Ps[w][c][phys * 8 + (qd & 1) * 4] = pv[kt];
            }

            // ---- O^T += VT P^T (16x16x32) ----
#pragma unroll
            for (int ks = 0; ks < 4; ks++) {
                bf16x8 pf = *(const bf16x8*)&Ps[w][c][((ks * 4 + qd) ^ sw) * 8];
#pragma unroll
                for (int dt = 0; dt < 4; dt++) {
                    bf16x8 vf = *(const bf16x8*)&VTs[dt * 16 + c][((ks * 4 + qd) ^ sw) * 8];
                    O[dt] = __builtin_amdgcn_mfma_f32_16x16x32_bf16(vf, pf, O[dt], 0, 0, 0);
                }
            }
        }

        // ---- epilogue: y[qrow][h*64 + d], 8B vector stores ----
        const float inv_l = 1.0f / l_i;
#pragma unroll
        for (int dt = 0; dt < 4; dt++) {
            bf16x4 ov;
#pragma unroll
            for (int r = 0; r < 4; r++) ov[r] = (bf16r)(O[dt][r] * inv_l);
            *(bf16x4*)(y + (size_t)qrow * C_DIM + h * 64 + dt * 16 + qd * 4) = ov;
        }
    }
}

// ---------------------------------------------------------------------------
// launch.  Inputs f32, output f32.  ws peak = 56 MiB (unchanged layout).
// ---------------------------------------------------------------------------
extern "C" void kernel_launch(void* const* d_in, const int* in_sizes, int n_in,
                              void* d_out, int out_size, void* d_ws, size_t ws_size,
                              hipStream_t stream) {
    const float* x        = (const float*)d_in[0];
    const float* attn_w   = (const float*)d_in[1];
    const float* ffn_w    = (const float*)d_in[2];
    const float* c_attn_w = (const float*)d_in[3];
    const float* c_proj_w = (const float*)d_in[4];
    const float* w1       = (const float*)d_in[5];
    const float* w2       = (const float*)d_in[6];
    const float* w3       = (const float*)d_in[7];
    float* xmid = (float*)d_out;

    char* ws = (char*)d_ws;
    bf16* cwA = (bf16*)(ws);
    bf16* cwP = (bf16*)(ws + MB(6));
    bf16* rms = (bf16*)(ws + MB(8));
    bf16* qkv = (bf16*)(ws + MB(16));
    bf16* VT  = (bf16*)(ws + MB(40));
    bf16* y   = (bf16*)(ws + MB(48));
    bf16* w1h = (bf16*)(ws + MB(16));
    bf16* w3h = (bf16*)(ws + MB(20));
    bf16* w2h = (bf16*)(ws + MB(24));
    bf16* h1h = (bf16*)(ws + MB(28));
    // work-queue counters live in the rms region: written AFTER step 3 has
    // consumed rms1, overwritten again only at step 6 (stream-ordered).
    int* ctrs = (int*)(ws + MB(8));

    // 1. attention weights -> bf16 (Q-proj rows x SCL: softmax scale folded)
    cvt_w<<<512, 256, 0, stream>>>(c_attn_w, 0, (ushort4*)cwA, 3072 * 1024 / 4,
                                   1024 * 1024 / 4, SCL);
    cvt_w<<<512, 256, 0, stream>>>(c_proj_w, 0, (ushort4*)cwP, 1024 * 1024 / 4, 0, 1.0f);
    // 2. rms1 = rmsnorm(x, attn_norm_w)
    rmsnorm_k<<<T_SEQ, 256, 0, stream>>>(x, attn_w, rms);
    // 3. qkv = rms1 @ c_attn^T   [4096, 3072]
    gemm128<0, 0><<<dim3(24, 32), 256, 0, stream>>>(rms, C_DIM, cwA, C_DIM, nullptr, qkv, 3072, 1024);
    // 4. VT (V transposed per head) + persistent-block flash attention v7
    build_tr<<<dim3(64, 16), 256, 0, stream>>>(qkv, VT, 2 * C_DIM);
    zero_ctr<<<1, 128, 0, stream>>>(ctrs);
    attn_mfma<<<768, 256, 0, stream>>>(qkv, VT, y, ctrs);
    // 5. xmid = x + y @ c_proj^T   (split-K=2, atomic f32 epilogue into
    //    xmid prefilled with x; grid 512 blocks = 2/CU instead of 1/CU)
    copy_f32<<<2048, 256, 0, stream>>>((const float4*)x, (float4*)xmid, T_SEQ * C_DIM / 4);
    gemm128<4, 1><<<dim3(8, 32, 2), 256, 0, stream>>>(y, C_DIM, cwP, C_DIM, nullptr, xmid, 1024, 512);
    // 6. rms2 = rmsnorm(xmid, ffn_norm_w)
    rmsnorm_k<<<T_SEQ, 256, 0, stream>>>(xmid, ffn_w, rms);
    // 7. FFN in two Hf=2048 halves: merged w1/w3 GEMM (fused f32 silu-mul,
    //    no h1 round-trip), then split-K=2 atomic w2 GEMM into xmid.
    for (int hh = 0; hh < 2; hh++) {
        cvt_w<<<512, 256, 0, stream>>>(w1, (size_t)hh * 2048 * 1024, (ushort4*)w1h,
                                       2048 * 1024 / 4, 0, 1.0f);
        cvt_w<<<512, 256, 0, stream>>>(w3, (size_t)hh * 2048 * 1024, (ushort4*)w3h,
                                       2048 * 1024 / 4, 0, 1.0f);
        gemm_w13<<<dim3(16, 32), 256, 0, stream>>>(rms, w1h, w3h, h1h, 2048, 1024);
        cvt_w2h<<<2048, 256, 0, stream>>>(w2, hh * 2048, (ushort4*)w2h);
        gemm128<4, 1><<<dim3(8, 32, 2), 256, 0, stream>>>(h1h, 2048, w2h, 2048, nullptr, xmid, 1024, 1024);
    }
}

// Round 7
// 499.133 us; speedup vs baseline: 1.2668x; 1.0192x over previous
//
#include <hip/hip_runtime.h>
#include <hip/hip_bf16.h>

typedef __hip_bfloat16 bf16;
typedef __bf16 bf16r;
typedef bf16r bf16x8 __attribute__((ext_vector_type(8)));
typedef bf16r bf16x4 __attribute__((ext_vector_type(4)));
typedef float f32x4 __attribute__((ext_vector_type(4)));

#define T_SEQ 4096
#define C_DIM 1024
#define LD_QKV 3072
#define MB(x) ((size_t)(x) << 20)
// 0.125 (1/sqrt(64)) * log2(e): softmax runs in exp2 domain.  Folded into the
// Q-projection weights at cvt time, so QK^T lands already log2-scaled.
#define SCL 0.18033688011112042f

static __device__ __forceinline__ unsigned short f2bf(float f) {
    bf16 h = (bf16)f;
    return *reinterpret_cast<unsigned short*>(&h);
}

// ---------------------------------------------------------------------------
// f32 -> bf16 weight convert, contiguous slice; first n4scl float4's are
// multiplied by scl (used to fold the attention scale into Q-proj rows).
// ---------------------------------------------------------------------------
__global__ __launch_bounds__(256) void cvt_w(const float* __restrict__ src, size_t eoff,
                                             ushort4* __restrict__ dst, int n4,
                                             int n4scl, float scl) {
    int i = blockIdx.x * 256 + threadIdx.x;
    const int stride = gridDim.x * 256;
    const float4* s = (const float4*)(src + eoff);
    for (; i < n4; i += stride) {
        float4 v = s[i];
        const float m = (i < n4scl) ? scl : 1.0f;
        ushort4 o;
        o.x = f2bf(v.x * m); o.y = f2bf(v.y * m); o.z = f2bf(v.z * m); o.w = f2bf(v.w * m);
        dst[i] = o;
    }
}

// ---------------------------------------------------------------------------
// f32 grid-stride copy (xmid = x prefill for the atomic split-K epilogues)
// ---------------------------------------------------------------------------
__global__ __launch_bounds__(256) void copy_f32(const float4* __restrict__ src,
                                                float4* __restrict__ dst, int n4) {
    int i = blockIdx.x * 256 + threadIdx.x;
    const int stride = gridDim.x * 256;
    for (; i < n4; i += stride) dst[i] = src[i];
}

// ---------------------------------------------------------------------------
// RMSNorm: f32 in, f32 weight, bf16 out. One block per row of 1024.
// ---------------------------------------------------------------------------
__global__ __launch_bounds__(256) void rmsnorm_k(const float* __restrict__ x,
                                                 const float* __restrict__ w,
                                                 bf16* __restrict__ out) {
    const int row = blockIdx.x;
    const int tid = threadIdx.x;
    const float* xr = x + (size_t)row * C_DIM;
    float v[4];
    float ss = 0.f;
#pragma unroll
    for (int i = 0; i < 4; i++) { v[i] = xr[tid * 4 + i]; ss += v[i] * v[i]; }
#pragma unroll
    for (int off = 32; off; off >>= 1) ss += __shfl_xor(ss, off);
    __shared__ float red[4];
    if ((tid & 63) == 0) red[tid >> 6] = ss;
    __syncthreads();
    const float tot = red[0] + red[1] + red[2] + red[3];
    const float scale = rsqrtf(tot * (1.0f / C_DIM) + 1e-6f);
#pragma unroll
    for (int i = 0; i < 4; i++) {
        const int c = tid * 4 + i;
        out[(size_t)row * C_DIM + c] = (bf16)(v[i] * scale * w[c]);
    }
}

// ---------------------------------------------------------------------------
// m97-structure GEMM: out[M,N] = A[M,K](lda) @ B[N,K](ldb)^T (+ epilogue).
// K is the PER-SLICE reduction length; blockIdx.z selects the K-slice
// (koff = z*K), enabling split-K for grid-starved shapes.  RESID==4: f32
// atomicAdd epilogue (out prefilled; slices race-free via atomics).
// ---------------------------------------------------------------------------
template <int RESID, int OUTF32>
__global__ __launch_bounds__(256) void gemm128(const bf16* __restrict__ A, int lda,
                                               const bf16* __restrict__ B, int ldb,
                                               const void* __restrict__ resid,
                                               void* __restrict__ out,
                                               int N, int K) {
    __shared__ __align__(16) bf16r As[128 * 32];
    __shared__ __align__(16) bf16r Bs[128 * 32];
    const int tid = threadIdx.x;
    const int w = tid >> 6, lane = tid & 63;
    const int c = lane & 15, qd = lane >> 4;
    const int wm = w >> 1, wn = w & 1;
    const int mbase = blockIdx.y * 128;
    const int nbase = blockIdx.x * 128;
    const size_t koff = (size_t)blockIdx.z * K;

    const int srow = lane >> 2, schk = lane & 3;
    const bf16* gA = A + (size_t)(mbase + w * 32 + srow) * lda + schk * 8 + koff;
    const bf16* gB = B + (size_t)(nbase + w * 32 + srow) * ldb + schk * 8 + koff;

    f32x4 acc[4][4] = {};

    for (int k0 = 0; k0 < K; k0 += 32) {
        __syncthreads();
#pragma unroll
        for (int s = 0; s < 2; s++) {
            __builtin_amdgcn_global_load_lds(
                (const __attribute__((address_space(1))) void*)(gA + (size_t)(s * 16) * lda + k0),
                (__attribute__((address_space(3))) void*)&As[(w * 32 + s * 16) * 32], 16, 0, 0);
            __builtin_amdgcn_global_load_lds(
                (const __attribute__((address_space(1))) void*)(gB + (size_t)(s * 16) * ldb + k0),
                (__attribute__((address_space(3))) void*)&Bs[(w * 32 + s * 16) * 32], 16, 0, 0);
        }
        __syncthreads();

        bf16x8 a[4], b[4];
#pragma unroll
        for (int i = 0; i < 4; i++)
            a[i] = *(const bf16x8*)&As[(wm * 64 + i * 16 + c) * 32 + qd * 8];
#pragma unroll
        for (int j = 0; j < 4; j++)
            b[j] = *(const bf16x8*)&Bs[(wn * 64 + j * 16 + c) * 32 + qd * 8];
#pragma unroll
        for (int i = 0; i < 4; i++)
#pragma unroll
            for (int j = 0; j < 4; j++)
                acc[i][j] = __builtin_amdgcn_mfma_f32_16x16x32_bf16(a[i], b[j], acc[i][j], 0, 0, 0);
    }

#pragma unroll
    for (int i = 0; i < 4; i++) {
#pragma unroll
        for (int j = 0; j < 4; j++) {
            const int col = nbase + wn * 64 + j * 16 + c;
#pragma unroll
            for (int reg = 0; reg < 4; reg++) {
                const int row = mbase + wm * 64 + i * 16 + qd * 4 + reg;
                const size_t idx = (size_t)row * N + col;
                float v = acc[i][j][reg];
                if (RESID == 2) v += ((const float*)resid)[idx];
                if (RESID == 3) {
                    const float a1 = (float)((const bf16*)resid)[idx];
                    v = (a1 / (1.0f + __expf(-a1))) * v;
                }
                if (RESID == 4) {
                    atomicAdd(&((float*)out)[idx], v);
                } else if (OUTF32) {
                    ((float*)out)[idx] = v;
                } else {
                    ((bf16*)out)[idx] = (bf16)v;
                }
            }
        }
    }
}

// ---------------------------------------------------------------------------
// Merged w1/w3 GEMM: h = silu(A@B1^T) * (A@B3^T), bf16 out [M, N].
// One A-staging feeds both B matrices; silu from f32 accumulators.
// Round 7: single pass N=4096 -> grid 32x32 = 1024 blocks (was 2 halves at
// 512 blocks each): full residency, half the A re-reads, 1 launch.
// ---------------------------------------------------------------------------
__global__ __launch_bounds__(256, 2) void gemm_w13(const bf16* __restrict__ A,
                                                   const bf16* __restrict__ B1,
                                                   const bf16* __restrict__ B3,
                                                   bf16* __restrict__ out,
                                                   int N, int K) {
    __shared__ __align__(16) bf16r As[128 * 32];
    __shared__ __align__(16) bf16r B1s[128 * 32];
    __shared__ __align__(16) bf16r B3s[128 * 32];
    const int tid = threadIdx.x;
    const int w = tid >> 6, lane = tid & 63;
    const int c = lane & 15, qd = lane >> 4;
    const int wm = w >> 1, wn = w & 1;
    const int mbase = blockIdx.y * 128;
    const int nbase = blockIdx.x * 128;

    const int srow = lane >> 2, schk = lane & 3;
    const bf16* gA = A + (size_t)(mbase + w * 32 + srow) * K + schk * 8;
    const bf16* gB1 = B1 + (size_t)(nbase + w * 32 + srow) * K + schk * 8;
    const bf16* gB3 = B3 + (size_t)(nbase + w * 32 + srow) * K + schk * 8;

    f32x4 acc1[4][4] = {};
    f32x4 acc3[4][4] = {};

    for (int k0 = 0; k0 < K; k0 += 32) {
        __syncthreads();
#pragma unroll
        for (int s = 0; s < 2; s++) {
            __builtin_amdgcn_global_load_lds(
                (const __attribute__((address_space(1))) void*)(gA + (size_t)(s * 16) * K + k0),
                (__attribute__((address_space(3))) void*)&As[(w * 32 + s * 16) * 32], 16, 0, 0);
            __builtin_amdgcn_global_load_lds(
                (const __attribute__((address_space(1))) void*)(gB1 + (size_t)(s * 16) * K + k0),
                (__attribute__((address_space(3))) void*)&B1s[(w * 32 + s * 16) * 32], 16, 0, 0);
            __builtin_amdgcn_global_load_lds(
                (const __attribute__((address_space(1))) void*)(gB3 + (size_t)(s * 16) * K + k0),
                (__attribute__((address_space(3))) void*)&B3s[(w * 32 + s * 16) * 32], 16, 0, 0);
        }
        __syncthreads();

        bf16x8 a[4], b1[4], b3[4];
#pragma unroll
        for (int i = 0; i < 4; i++)
            a[i] = *(const bf16x8*)&As[(wm * 64 + i * 16 + c) * 32 + qd * 8];
#pragma unroll
        for (int j = 0; j < 4; j++) {
            b1[j] = *(const bf16x8*)&B1s[(wn * 64 + j * 16 + c) * 32 + qd * 8];
            b3[j] = *(const bf16x8*)&B3s[(wn * 64 + j * 16 + c) * 32 + qd * 8];
        }
#pragma unroll
        for (int i = 0; i < 4; i++)
#pragma unroll
            for (int j = 0; j < 4; j++) {
                acc1[i][j] = __builtin_amdgcn_mfma_f32_16x16x32_bf16(a[i], b1[j], acc1[i][j], 0, 0, 0);
                acc3[i][j] = __builtin_amdgcn_mfma_f32_16x16x32_bf16(a[i], b3[j], acc3[i][j], 0, 0, 0);
            }
    }

#pragma unroll
    for (int i = 0; i < 4; i++) {
#pragma unroll
        for (int j = 0; j < 4; j++) {
            const int col = nbase + wn * 64 + j * 16 + c;
#pragma unroll
            for (int reg = 0; reg < 4; reg++) {
                const int row = mbase + wm * 64 + i * 16 + qd * 4 + reg;
                const float a1 = acc1[i][j][reg];
                const float h = (a1 / (1.0f + __expf(-a1))) * acc3[i][j][reg];
                out[(size_t)row * N + col] = (bf16)h;
            }
        }
    }
}

// ---------------------------------------------------------------------------
// Transpose a qkv section to [h][d][t]
// ---------------------------------------------------------------------------
__global__ __launch_bounds__(256) void build_tr(const bf16* __restrict__ qkv,
                                                bf16* __restrict__ dst, int soff) {
    const int h = blockIdx.y;
    const int tb = blockIdx.x;
    __shared__ bf16 tile[64][65];
    const int tx = threadIdx.x & 63;
    const int ty = threadIdx.x >> 6;
    for (int rr = ty; rr < 64; rr += 4)
        tile[rr][tx] = qkv[(size_t)(tb * 64 + rr) * LD_QKV + soff + h * 64 + tx];
    __syncthreads();
    for (int rr = ty; rr < 64; rr += 4)
        dst[((size_t)h * 64 + rr) * T_SEQ + tb * 64 + tx] = tile[tx][rr];
}

// ---------------------------------------------------------------------------
// zero the 8 per-queue work counters (64B-padded: one cache line each)
// ---------------------------------------------------------------------------
#define CTR_STRIDE 16  // ints; 64 B
__global__ void zero_ctr(int* p) { if (threadIdx.x < 8 * CTR_STRIDE) p[threadIdx.x] = 0; }

// ---------------------------------------------------------------------------
// MFMA flash attention v8 = v7 (persistent blocks + 8 LPT work queues +
// scale-folded exp2 softmax + defer-max) with staging moved to
// global_load_lds (single buffer, 48 KB, 3 blocks/CU preserved).
// The serial global->reg->ds_write staging (8 loads + 8 ds_writes + dual
// address math per thread per chunk) becomes 8 fused gload_lds issues.
// Swizzle preserved via pre-swizzled GLOBAL source + linear LDS dest
// (v5 verified this exact mapping end-to-end); all frag reads unchanged.
// ---------------------------------------------------------------------------
__global__ __launch_bounds__(256) void attn_mfma(const bf16* __restrict__ qkv,
                                                 const bf16* __restrict__ VT,
                                                 bf16* __restrict__ y,
                                                 int* __restrict__ ctrs) {
    __shared__ __align__(16) bf16r Ks[128][64];    // keys x d
    __shared__ __align__(16) bf16r VTs[64][128];   // d x keys
    __shared__ __align__(16) bf16r Ps[4][16][128]; // per-wave q x keys
    __shared__ int s_wi;

    const int tid  = threadIdx.x;
    const int w    = tid >> 6;
    const int lane = tid & 63;
    const int c    = lane & 15;
    const int qd   = lane >> 4;
    const int sw   = c & 7;            // xor swizzle key for frag reads
    const int qi   = blockIdx.x & 7;   // queue = presumed XCD
    int* ctr = ctrs + qi * CTR_STRIDE;

    // Per-lane staging coords: each gload_lds covers 64 lanes x 16B = 1 KB.
    // K tile: 8 rows/group (128B rows); VT tile: 4 rows/group (256B rows).
    const int k_ri = lane >> 3, k_pc = lane & 7;
    const int v_ri = lane >> 4, v_pc = lane & 15;

    while (true) {
        __syncthreads();               // LDS + s_wi safe to reuse
        if (tid == 0) s_wi = atomicAdd(ctr, 1);
        __syncthreads();
        const int j = s_wi;
        if (j >= 128) break;           // queue drained (uniform exit)

        const int h    = qi + 8 * (j & 1);      // heads {qi, qi+8}
        const int qb   = 63 - (j >> 1);         // largest-first (LPT)
        const int qrow = qb * 64 + w * 16 + c;

        // Q B-frags: lane holds Q[qrow][ks*32 + qd*8 + jj]  (pre-scaled by SCL)
        bf16x8 qf[2];
        {
            const bf16* qp = qkv + (size_t)qrow * LD_QKV + h * 64;
            qf[0] = *(const bf16x8*)(qp + qd * 8);
            qf[1] = *(const bf16x8*)(qp + 32 + qd * 8);
        }

        f32x4 O[4] = {};               // O^T: D[row=d=dt*16+qd*4+r][col=q=c]
        float m_i = -1e30f, l_i = 0.f; // m_i in log2 domain
        const int nkb = (qb >> 1) + 1; // 128-key chunks

        for (int kb = 0; kb < nkb; kb++) {
            __syncthreads();           // prior iteration's LDS reads done
            // ---- stage chunk kb via global_load_lds (pre-swizzled src) ----
#pragma unroll
            for (int ii = 0; ii < 4; ii++) {
                const int grp = w * 4 + ii;             // 0..15
                const int kr = grp * 8 + k_ri;          // 0..127
                const int kch = k_pc ^ (kr & 7);
                __builtin_amdgcn_global_load_lds(
                    (const __attribute__((address_space(1))) void*)
                        (qkv + (size_t)(kb * 128 + kr) * LD_QKV + C_DIM + h * 64 + kch * 8),
                    (__attribute__((address_space(3))) void*)&Ks[grp * 8][0], 16, 0, 0);
                const int vr = grp * 4 + v_ri;          // 0..63
                const int vch = v_pc ^ (vr & 7);
                __builtin_amdgcn_global_load_lds(
                    (const __attribute__((address_space(1))) void*)
                        (VT + ((size_t)h * 64 + vr) * T_SEQ + kb * 128 + vch * 8),
                    (__attribute__((address_space(3))) void*)&VTs[grp * 4][0], 16, 0, 0);
            }
            asm volatile("s_waitcnt vmcnt(0)" ::: "memory");
            __syncthreads();

            // ---- S^T = K Q^T : rows = keys (kt*16+qd*4+r), cols = q (c) ----
            f32x4 ST[8];
#pragma unroll
            for (int kt = 0; kt < 8; kt++) {
                f32x4 z = {};
#pragma unroll
                for (int ks = 0; ks < 2; ks++) {
                    bf16x8 kf = *(const bf16x8*)&Ks[kt * 16 + c][((ks * 4 + qd) ^ sw) * 8];
                    z = __builtin_amdgcn_mfma_f32_16x16x32_bf16(kf, qf[ks], z, 0, 0, 0);
                }
                ST[kt] = z;
            }

            // ---- causal mask on the diagonal chunk only ----
            if (kb == nkb - 1) {
#pragma unroll
                for (int kt = 0; kt < 8; kt++)
#pragma unroll
                    for (int r = 0; r < 4; r++)
                        if (kb * 128 + kt * 16 + qd * 4 + r > qrow) ST[kt][r] = -1e30f;
            }

            // ---- online softmax (exp2 domain), per-lane scalar stats ----
            float mb = -1e30f;
#pragma unroll
            for (int kt = 0; kt < 8; kt++)
#pragma unroll
                for (int r = 0; r < 4; r++) mb = fmaxf(mb, ST[kt][r]);
            mb = fmaxf(mb, __shfl_xor(mb, 16));
            mb = fmaxf(mb, __shfl_xor(mb, 32));

            bf16x4 pv[8];
            float rs = 0.f;
            if (__all(mb - m_i <= 8.0f)) {
                // defer-max: keep m_i, skip alpha-rescale; P bounded by 2^8
#pragma unroll
                for (int kt = 0; kt < 8; kt++)
#pragma unroll
                    for (int r = 0; r < 4; r++) {
                        const float p = exp2f(ST[kt][r] - m_i);
                        pv[kt][r] = (bf16r)p;
                        rs += p;
                    }
                rs += __shfl_xor(rs, 16);
                rs += __shfl_xor(rs, 32);
                l_i += rs;
            } else {
                const float mnew = fmaxf(m_i, mb);
                const float alpha = exp2f(m_i - mnew);
#pragma unroll
                for (int kt = 0; kt < 8; kt++)
#pragma unroll
                    for (int r = 0; r < 4; r++) {
                        const float p = exp2f(ST[kt][r] - mnew);
                        pv[kt][r] = (bf16r)p;
                        rs += p;
                    }
                rs += __shfl_xor(rs, 16);
                rs += __shfl_xor(rs, 32);
                l_i = l_i * alpha + rs;
                m_i = mnew;
#pragma unroll
                for (int dt = 0; dt < 4; dt++)
#pragma unroll
                    for (int r = 0; r < 4; r++) O[dt][r] *= alpha;
            }

            // ---- P^T -> Ps[q][key] via 8B vector writes (wave-private) ----
#pragma unroll
            for (int kt = 0; kt < 8; kt++) {
                const int phys = (kt * 2 + (qd >> 1)) ^ sw;  // 16B-chunk swizzle
                *(bf16x4*)&Ps[w][c][phys * 8 + (qd & 1) * 4] = pv[kt];
            }

            // ---- O^T += VT P^T (16x16x32) ----
#pragma unroll
            for (int ks = 0; ks < 4; ks++) {
                bf16x8 pf = *(const bf16x8*)&Ps[w][c][((ks * 4 + qd) ^ sw) * 8];
#pragma unroll
                for (int dt = 0; dt < 4; dt++) {
                    bf16x8 vf = *(const bf16x8*)&VTs[dt * 16 + c][((ks * 4 + qd) ^ sw) * 8];
                    O[dt] = __builtin_amdgcn_mfma_f32_16x16x32_bf16(vf, pf, O[dt], 0, 0, 0);
                }
            }
        }

        // ---- epilogue: y[qrow][h*64 + d], 8B vector stores ----
        const float inv_l = 1.0f / l_i;
#pragma unroll
        for (int dt = 0; dt < 4; dt++) {
            bf16x4 ov;
#pragma unroll
            for (int r = 0; r < 4; r++) ov[r] = (bf16r)(O[dt][r] * inv_l);
            *(bf16x4*)(y + (size_t)qrow * C_DIM + h * 64 + dt * 16 + qd * 4) = ov;
        }
    }
}

// ---------------------------------------------------------------------------
// launch.  Inputs f32, output f32.  ws peak = 56 MiB.
//
// Region timeline (all transitions stream-ordered, audited):
//   0..6   cwA        -> (dead after qkv gemm) -> rms2 [0..8] after proj
//   6..8   cwP        -> (needed by proj)      -> part of rms2
//   8..16  rms1/ctrs  -> (dead after qkv/attn) -> W1 -> (dead after w13) -> W2
//   16..40 qkv        -> (dead after attn)     -> W3 [16..24], h1 tail
//   40..48 VT         -> (dead after attn)     -> h1
//   48..56 y          -> (dead after proj)     -> h1
//   24..56 h1 [4096][4096] bf16 (32 MB), written by w13 after proj.
// ---------------------------------------------------------------------------
extern "C" void kernel_launch(void* const* d_in, const int* in_sizes, int n_in,
                              void* d_out, int out_size, void* d_ws, size_t ws_size,
                              hipStream_t stream) {
    const float* x        = (const float*)d_in[0];
    const float* attn_w   = (const float*)d_in[1];
    const float* ffn_w    = (const float*)d_in[2];
    const float* c_attn_w = (const float*)d_in[3];
    const float* c_proj_w = (const float*)d_in[4];
    const float* w1       = (const float*)d_in[5];
    const float* w2       = (const float*)d_in[6];
    const float* w3       = (const float*)d_in[7];
    float* xmid = (float*)d_out;

    char* ws = (char*)d_ws;
    bf16* cwA  = (bf16*)(ws);            // 0..6
    bf16* cwP  = (bf16*)(ws + MB(6));    // 6..8
    bf16* rms1 = (bf16*)(ws + MB(8));    // 8..16
    bf16* qkv  = (bf16*)(ws + MB(16));   // 16..40
    bf16* VT   = (bf16*)(ws + MB(40));   // 40..48
    bf16* y    = (bf16*)(ws + MB(48));   // 48..56
    int*  ctrs = (int*)(ws + MB(8));     // over rms1 (dead after qkv gemm)
    bf16* rms2 = (bf16*)(ws);            // 0..8 (over cwA/cwP, after proj)
    bf16* w1h  = (bf16*)(ws + MB(8));    // 8..16 (over rms1/ctrs, after attn)
    bf16* w3h  = (bf16*)(ws + MB(16));   // 16..24 (over qkv, after attn)
    bf16* w2h  = (bf16*)(ws + MB(8));    // 8..16 (over w1h, after w13)
    bf16* h1   = (bf16*)(ws + MB(24));   // 24..56 (over qkv tail/VT/y)

    // 1. attention weights -> bf16 (Q-proj rows x SCL: softmax scale folded)
    cvt_w<<<512, 256, 0, stream>>>(c_attn_w, 0, (ushort4*)cwA, 3072 * 1024 / 4,
                                   1024 * 1024 / 4, SCL);
    cvt_w<<<512, 256, 0, stream>>>(c_proj_w, 0, (ushort4*)cwP, 1024 * 1024 / 4, 0, 1.0f);
    // 2. rms1 = rmsnorm(x, attn_norm_w)
    rmsnorm_k<<<T_SEQ, 256, 0, stream>>>(x, attn_w, rms1);
    // 3. qkv = rms1 @ c_attn^T   [4096, 3072]
    gemm128<0, 0><<<dim3(24, 32), 256, 0, stream>>>(rms1, C_DIM, cwA, C_DIM, nullptr, qkv, 3072, 1024);
    // 4. VT (V transposed per head) + persistent-block flash attention v8
    build_tr<<<dim3(64, 16), 256, 0, stream>>>(qkv, VT, 2 * C_DIM);
    zero_ctr<<<1, 128, 0, stream>>>(ctrs);
    attn_mfma<<<768, 256, 0, stream>>>(qkv, VT, y, ctrs);
    // 5. FFN weight converts (regions dead after attn), xmid = x prefill
    cvt_w<<<512, 256, 0, stream>>>(w1, 0, (ushort4*)w1h, 4096 * 1024 / 4, 0, 1.0f);
    cvt_w<<<512, 256, 0, stream>>>(w3, 0, (ushort4*)w3h, 4096 * 1024 / 4, 0, 1.0f);
    copy_f32<<<2048, 256, 0, stream>>>((const float4*)x, (float4*)xmid, T_SEQ * C_DIM / 4);
    // 6. xmid += y @ c_proj^T   (split-K=2 atomic; 512 blocks = 2/CU)
    gemm128<4, 1><<<dim3(8, 32, 2), 256, 0, stream>>>(y, C_DIM, cwP, C_DIM, nullptr, xmid, 1024, 512);
    // 7. rms2 = rmsnorm(xmid, ffn_norm_w)   (into 0..8, cwA/cwP dead)
    rmsnorm_k<<<T_SEQ, 256, 0, stream>>>(xmid, ffn_w, rms2);
    // 8. h1 = silu(rms2@w1^T)*(rms2@w3^T), single pass N=4096 (1024 blocks)
    gemm_w13<<<dim3(32, 32), 256, 0, stream>>>(rms2, w1h, w3h, h1, 4096, 1024);
    // 9. xmid += h1 @ w2^T   (full K=4096, split-K=4 atomic; 1024 blocks)
    cvt_w<<<512, 256, 0, stream>>>(w2, 0, (ushort4*)w2h, 1024 * 4096 / 4, 0, 1.0f);
    gemm128<4, 1><<<dim3(8, 32, 4), 256, 0, stream>>>(h1, 4096, w2h, 4096, nullptr, xmid, 1024, 1024);
}

// Round 8
// 483.875 us; speedup vs baseline: 1.3068x; 1.0315x over previous
//
#include <hip/hip_runtime.h>
#include <hip/hip_bf16.h>

typedef __hip_bfloat16 bf16;
typedef __bf16 bf16r;
typedef bf16r bf16x8 __attribute__((ext_vector_type(8)));
typedef bf16r bf16x4 __attribute__((ext_vector_type(4)));
typedef float f32x4 __attribute__((ext_vector_type(4)));

#define T_SEQ 4096
#define C_DIM 1024
#define LD_QKV 3072
#define MB(x) ((size_t)(x) << 20)
// 0.125 (1/sqrt(64)) * log2(e): softmax runs in exp2 domain.  Folded into the
// Q-projection weights at cvt time, so QK^T lands already log2-scaled.
#define SCL 0.18033688011112042f

static __device__ __forceinline__ unsigned short f2bf(float f) {
    bf16 h = (bf16)f;
    return *reinterpret_cast<unsigned short*>(&h);
}

// ---------------------------------------------------------------------------
// f32 -> bf16 weight convert, contiguous slice; first n4scl float4's are
// multiplied by scl (used to fold the attention scale into Q-proj rows).
// ---------------------------------------------------------------------------
__global__ __launch_bounds__(256) void cvt_w(const float* __restrict__ src, size_t eoff,
                                             ushort4* __restrict__ dst, int n4,
                                             int n4scl, float scl) {
    int i = blockIdx.x * 256 + threadIdx.x;
    const int stride = gridDim.x * 256;
    const float4* s = (const float4*)(src + eoff);
    for (; i < n4; i += stride) {
        float4 v = s[i];
        const float m = (i < n4scl) ? scl : 1.0f;
        ushort4 o;
        o.x = f2bf(v.x * m); o.y = f2bf(v.y * m); o.z = f2bf(v.z * m); o.w = f2bf(v.w * m);
        dst[i] = o;
    }
}

// ---------------------------------------------------------------------------
// f32 grid-stride copy (xmid = x prefill for the atomic split-K epilogues)
// ---------------------------------------------------------------------------
__global__ __launch_bounds__(256) void copy_f32(const float4* __restrict__ src,
                                                float4* __restrict__ dst, int n4) {
    int i = blockIdx.x * 256 + threadIdx.x;
    const int stride = gridDim.x * 256;
    for (; i < n4; i += stride) dst[i] = src[i];
}

// ---------------------------------------------------------------------------
// RMSNorm: f32 in, f32 weight, bf16 out. One block per row of 1024.
// ---------------------------------------------------------------------------
__global__ __launch_bounds__(256) void rmsnorm_k(const float* __restrict__ x,
                                                 const float* __restrict__ w,
                                                 bf16* __restrict__ out) {
    const int row = blockIdx.x;
    const int tid = threadIdx.x;
    const float* xr = x + (size_t)row * C_DIM;
    float v[4];
    float ss = 0.f;
#pragma unroll
    for (int i = 0; i < 4; i++) { v[i] = xr[tid * 4 + i]; ss += v[i] * v[i]; }
#pragma unroll
    for (int off = 32; off; off >>= 1) ss += __shfl_xor(ss, off);
    __shared__ float red[4];
    if ((tid & 63) == 0) red[tid >> 6] = ss;
    __syncthreads();
    const float tot = red[0] + red[1] + red[2] + red[3];
    const float scale = rsqrtf(tot * (1.0f / C_DIM) + 1e-6f);
#pragma unroll
    for (int i = 0; i < 4; i++) {
        const int c = tid * 4 + i;
        out[(size_t)row * C_DIM + c] = (bf16)(v[i] * scale * w[c]);
    }
}

// ---------------------------------------------------------------------------
// m97-structure GEMM: out[M,N] = A[M,K](lda) @ B[N,K](ldb)^T (+ epilogue).
// K is the PER-SLICE reduction length; blockIdx.z selects the K-slice
// (koff = z*K), enabling split-K for grid-starved shapes.  RESID==4: f32
// atomicAdd epilogue (out prefilled; slices race-free via atomics).
// ---------------------------------------------------------------------------
template <int RESID, int OUTF32>
__global__ __launch_bounds__(256) void gemm128(const bf16* __restrict__ A, int lda,
                                               const bf16* __restrict__ B, int ldb,
                                               const void* __restrict__ resid,
                                               void* __restrict__ out,
                                               int N, int K) {
    __shared__ __align__(16) bf16r As[128 * 32];
    __shared__ __align__(16) bf16r Bs[128 * 32];
    const int tid = threadIdx.x;
    const int w = tid >> 6, lane = tid & 63;
    const int c = lane & 15, qd = lane >> 4;
    const int wm = w >> 1, wn = w & 1;
    const int mbase = blockIdx.y * 128;
    const int nbase = blockIdx.x * 128;
    const size_t koff = (size_t)blockIdx.z * K;

    const int srow = lane >> 2, schk = lane & 3;
    const bf16* gA = A + (size_t)(mbase + w * 32 + srow) * lda + schk * 8 + koff;
    const bf16* gB = B + (size_t)(nbase + w * 32 + srow) * ldb + schk * 8 + koff;

    f32x4 acc[4][4] = {};

    for (int k0 = 0; k0 < K; k0 += 32) {
        __syncthreads();
#pragma unroll
        for (int s = 0; s < 2; s++) {
            __builtin_amdgcn_global_load_lds(
                (const __attribute__((address_space(1))) void*)(gA + (size_t)(s * 16) * lda + k0),
                (__attribute__((address_space(3))) void*)&As[(w * 32 + s * 16) * 32], 16, 0, 0);
            __builtin_amdgcn_global_load_lds(
                (const __attribute__((address_space(1))) void*)(gB + (size_t)(s * 16) * ldb + k0),
                (__attribute__((address_space(3))) void*)&Bs[(w * 32 + s * 16) * 32], 16, 0, 0);
        }
        __syncthreads();

        bf16x8 a[4], b[4];
#pragma unroll
        for (int i = 0; i < 4; i++)
            a[i] = *(const bf16x8*)&As[(wm * 64 + i * 16 + c) * 32 + qd * 8];
#pragma unroll
        for (int j = 0; j < 4; j++)
            b[j] = *(const bf16x8*)&Bs[(wn * 64 + j * 16 + c) * 32 + qd * 8];
#pragma unroll
        for (int i = 0; i < 4; i++)
#pragma unroll
            for (int j = 0; j < 4; j++)
                acc[i][j] = __builtin_amdgcn_mfma_f32_16x16x32_bf16(a[i], b[j], acc[i][j], 0, 0, 0);
    }

#pragma unroll
    for (int i = 0; i < 4; i++) {
#pragma unroll
        for (int j = 0; j < 4; j++) {
            const int col = nbase + wn * 64 + j * 16 + c;
#pragma unroll
            for (int reg = 0; reg < 4; reg++) {
                const int row = mbase + wm * 64 + i * 16 + qd * 4 + reg;
                const size_t idx = (size_t)row * N + col;
                float v = acc[i][j][reg];
                if (RESID == 2) v += ((const float*)resid)[idx];
                if (RESID == 3) {
                    const float a1 = (float)((const bf16*)resid)[idx];
                    v = (a1 / (1.0f + __expf(-a1))) * v;
                }
                if (RESID == 4) {
                    atomicAdd(&((float*)out)[idx], v);
                } else if (OUTF32) {
                    ((float*)out)[idx] = v;
                } else {
                    ((bf16*)out)[idx] = (bf16)v;
                }
            }
        }
    }
}

// ---------------------------------------------------------------------------
// Merged w1/w3 GEMM: h = silu(A@B1^T) * (A@B3^T), bf16 out [M, N].
// One A-staging feeds both B matrices; silu from f32 accumulators.
// Single pass N=4096 -> grid 32x32 = 1024 blocks = 4/CU.
// ---------------------------------------------------------------------------
__global__ __launch_bounds__(256, 2) void gemm_w13(const bf16* __restrict__ A,
                                                   const bf16* __restrict__ B1,
                                                   const bf16* __restrict__ B3,
                                                   bf16* __restrict__ out,
                                                   int N, int K) {
    __shared__ __align__(16) bf16r As[128 * 32];
    __shared__ __align__(16) bf16r B1s[128 * 32];
    __shared__ __align__(16) bf16r B3s[128 * 32];
    const int tid = threadIdx.x;
    const int w = tid >> 6, lane = tid & 63;
    const int c = lane & 15, qd = lane >> 4;
    const int wm = w >> 1, wn = w & 1;
    const int mbase = blockIdx.y * 128;
    const int nbase = blockIdx.x * 128;

    const int srow = lane >> 2, schk = lane & 3;
    const bf16* gA = A + (size_t)(mbase + w * 32 + srow) * K + schk * 8;
    const bf16* gB1 = B1 + (size_t)(nbase + w * 32 + srow) * K + schk * 8;
    const bf16* gB3 = B3 + (size_t)(nbase + w * 32 + srow) * K + schk * 8;

    f32x4 acc1[4][4] = {};
    f32x4 acc3[4][4] = {};

    for (int k0 = 0; k0 < K; k0 += 32) {
        __syncthreads();
#pragma unroll
        for (int s = 0; s < 2; s++) {
            __builtin_amdgcn_global_load_lds(
                (const __attribute__((address_space(1))) void*)(gA + (size_t)(s * 16) * K + k0),
                (__attribute__((address_space(3))) void*)&As[(w * 32 + s * 16) * 32], 16, 0, 0);
            __builtin_amdgcn_global_load_lds(
                (const __attribute__((address_space(1))) void*)(gB1 + (size_t)(s * 16) * K + k0),
                (__attribute__((address_space(3))) void*)&B1s[(w * 32 + s * 16) * 32], 16, 0, 0);
            __builtin_amdgcn_global_load_lds(
                (const __attribute__((address_space(1))) void*)(gB3 + (size_t)(s * 16) * K + k0),
                (__attribute__((address_space(3))) void*)&B3s[(w * 32 + s * 16) * 32], 16, 0, 0);
        }
        __syncthreads();

        bf16x8 a[4], b1[4], b3[4];
#pragma unroll
        for (int i = 0; i < 4; i++)
            a[i] = *(const bf16x8*)&As[(wm * 64 + i * 16 + c) * 32 + qd * 8];
#pragma unroll
        for (int j = 0; j < 4; j++) {
            b1[j] = *(const bf16x8*)&B1s[(wn * 64 + j * 16 + c) * 32 + qd * 8];
            b3[j] = *(const bf16x8*)&B3s[(wn * 64 + j * 16 + c) * 32 + qd * 8];
        }
#pragma unroll
        for (int i = 0; i < 4; i++)
#pragma unroll
            for (int j = 0; j < 4; j++) {
                acc1[i][j] = __builtin_amdgcn_mfma_f32_16x16x32_bf16(a[i], b1[j], acc1[i][j], 0, 0, 0);
                acc3[i][j] = __builtin_amdgcn_mfma_f32_16x16x32_bf16(a[i], b3[j], acc3[i][j], 0, 0, 0);
            }
    }

#pragma unroll
    for (int i = 0; i < 4; i++) {
#pragma unroll
        for (int j = 0; j < 4; j++) {
            const int col = nbase + wn * 64 + j * 16 + c;
#pragma unroll
            for (int reg = 0; reg < 4; reg++) {
                const int row = mbase + wm * 64 + i * 16 + qd * 4 + reg;
                const float a1 = acc1[i][j][reg];
                const float h = (a1 / (1.0f + __expf(-a1))) * acc3[i][j][reg];
                out[(size_t)row * N + col] = (bf16)h;
            }
        }
    }
}

// ---------------------------------------------------------------------------
// Transpose a qkv section to [h][d][t]
// ---------------------------------------------------------------------------
__global__ __launch_bounds__(256) void build_tr(const bf16* __restrict__ qkv,
                                                bf16* __restrict__ dst, int soff) {
    const int h = blockIdx.y;
    const int tb = blockIdx.x;
    __shared__ bf16 tile[64][65];
    const int tx = threadIdx.x & 63;
    const int ty = threadIdx.x >> 6;
    for (int rr = ty; rr < 64; rr += 4)
        tile[rr][tx] = qkv[(size_t)(tb * 64 + rr) * LD_QKV + soff + h * 64 + tx];
    __syncthreads();
    for (int rr = ty; rr < 64; rr += 4)
        dst[((size_t)h * 64 + rr) * T_SEQ + tb * 64 + tx] = tile[tx][rr];
}

// ---------------------------------------------------------------------------
// zero the 8 per-queue work counters (64B-padded: one cache line each)
// ---------------------------------------------------------------------------
#define CTR_STRIDE 16  // ints; 64 B
__global__ void zero_ctr(int* p) { if (threadIdx.x < 8 * CTR_STRIDE) p[threadIdx.x] = 0; }

// ---------------------------------------------------------------------------
// MFMA flash attention v9 = v7 body restored (persistent blocks + 8 LPT work
// queues + scale-folded exp2 softmax + defer-max + SERIAL REG-STAGING).
//
// Round-7 post-mortem: gload_lds staging REGRESSED attn 100.7 -> 117.4 us.
// VALU-busy time was unchanged (~53 us both ways) -- staging VALU was never
// the cost; gload_lds + vmcnt(0) serialized the load drain, where the
// compiler pipelines reg-staging's load->ds_write pairs with counted
// vmcnt(N).  Reg-staging (100.7 us) is the measured minimum of the three
// staging variants (reg 100.7 < gload_lds 117.4 < dbuf-gload 151).
// ---------------------------------------------------------------------------
__global__ __launch_bounds__(256) void attn_mfma(const bf16* __restrict__ qkv,
                                                 const bf16* __restrict__ VT,
                                                 bf16* __restrict__ y,
                                                 int* __restrict__ ctrs) {
    __shared__ __align__(16) bf16r Ks[128][64];    // keys x d
    __shared__ __align__(16) bf16r VTs[64][128];   // d x keys
    __shared__ __align__(16) bf16r Ps[4][16][128]; // per-wave q x keys
    __shared__ int s_wi;

    const int tid  = threadIdx.x;
    const int w    = tid >> 6;
    const int lane = tid & 63;
    const int c    = lane & 15;
    const int qd   = lane >> 4;
    const int sw   = c & 7;            // xor swizzle key for frag reads
    const int qi   = blockIdx.x & 7;   // queue = presumed XCD
    int* ctr = ctrs + qi * CTR_STRIDE;

    while (true) {
        __syncthreads();               // LDS + s_wi safe to reuse
        if (tid == 0) s_wi = atomicAdd(ctr, 1);
        __syncthreads();
        const int j = s_wi;
        if (j >= 128) break;           // queue drained (uniform exit)

        const int h    = qi + 8 * (j & 1);      // heads {qi, qi+8}
        const int qb   = 63 - (j >> 1);         // largest-first (LPT)
        const int qrow = qb * 64 + w * 16 + c;

        // Q B-frags: lane holds Q[qrow][ks*32 + qd*8 + jj]  (pre-scaled by SCL)
        bf16x8 qf[2];
        {
            const bf16* qp = qkv + (size_t)qrow * LD_QKV + h * 64;
            qf[0] = *(const bf16x8*)(qp + qd * 8);
            qf[1] = *(const bf16x8*)(qp + 32 + qd * 8);
        }

        f32x4 O[4] = {};               // O^T: D[row=d=dt*16+qd*4+r][col=q=c]
        float m_i = -1e30f, l_i = 0.f; // m_i in log2 domain
        const int nkb = (qb >> 1) + 1; // 128-key chunks

        for (int kb = 0; kb < nkb; kb++) {
            __syncthreads();           // prior iteration's LDS reads done
#pragma unroll
            for (int ii = 0; ii < 4; ii++) {
                const int i = ii * 256 + tid;
                const int kr = i >> 3, ch = i & 7;    // K: 128 rows x 8 chunks
                *(bf16x8*)&Ks[kr][(ch ^ (kr & 7)) * 8] =
                    *(const bf16x8*)(qkv + (size_t)(kb * 128 + kr) * LD_QKV + C_DIM + h * 64 + ch * 8);
                const int vr = i >> 4, vch = i & 15;  // VT: 64 rows x 16 chunks
                *(bf16x8*)&VTs[vr][(vch ^ (vr & 7)) * 8] =
                    *(const bf16x8*)(VT + ((size_t)h * 64 + vr) * T_SEQ + kb * 128 + vch * 8);
            }
            __syncthreads();

            // ---- S^T = K Q^T : rows = keys (kt*16+qd*4+r), cols = q (c) ----
            f32x4 ST[8];
#pragma unroll
            for (int kt = 0; kt < 8; kt++) {
                f32x4 z = {};
#pragma unroll
                for (int ks = 0; ks < 2; ks++) {
                    bf16x8 kf = *(const bf16x8*)&Ks[kt * 16 + c][((ks * 4 + qd) ^ sw) * 8];
                    z = __builtin_amdgcn_mfma_f32_16x16x32_bf16(kf, qf[ks], z, 0, 0, 0);
                }
                ST[kt] = z;
            }

            // ---- causal mask on the diagonal chunk only ----
            if (kb == nkb - 1) {
#pragma unroll
                for (int kt = 0; kt < 8; kt++)
#pragma unroll
                    for (int r = 0; r < 4; r++)
                        if (kb * 128 + kt * 16 + qd * 4 + r > qrow) ST[kt][r] = -1e30f;
            }

            // ---- online softmax (exp2 domain), per-lane scalar stats ----
            float mb = -1e30f;
#pragma unroll
            for (int kt = 0; kt < 8; kt++)
#pragma unroll
                for (int r = 0; r < 4; r++) mb = fmaxf(mb, ST[kt][r]);
            mb = fmaxf(mb, __shfl_xor(mb, 16));
            mb = fmaxf(mb, __shfl_xor(mb, 32));

            bf16x4 pv[8];
            float rs = 0.f;
            if (__all(mb - m_i <= 8.0f)) {
                // defer-max: keep m_i, skip alpha-rescale; P bounded by 2^8
#pragma unroll
                for (int kt = 0; kt < 8; kt++)
#pragma unroll
                    for (int r = 0; r < 4; r++) {
                        const float p = exp2f(ST[kt][r] - m_i);
                        pv[kt][r] = (bf16r)p;
                        rs += p;
                    }
                rs += __shfl_xor(rs, 16);
                rs += __shfl_xor(rs, 32);
                l_i += rs;
            } else {
                const float mnew = fmaxf(m_i, mb);
                const float alpha = exp2f(m_i - mnew);
#pragma unroll
                for (int kt = 0; kt < 8; kt++)
#pragma unroll
                    for (int r = 0; r < 4; r++) {
                        const float p = exp2f(ST[kt][r] - mnew);
                        pv[kt][r] = (bf16r)p;
                        rs += p;
                    }
                rs += __shfl_xor(rs, 16);
                rs += __shfl_xor(rs, 32);
                l_i = l_i * alpha + rs;
                m_i = mnew;
#pragma unroll
                for (int dt = 0; dt < 4; dt++)
#pragma unroll
                    for (int r = 0; r < 4; r++) O[dt][r] *= alpha;
            }

            // ---- P^T -> Ps[q][key] via 8B vector writes (wave-private) ----
#pragma unroll
            for (int kt = 0; kt < 8; kt++) {
                const int phys = (kt * 2 + (qd >> 1)) ^ sw;  // 16B-chunk swizzle
                *(bf16x4*)&Ps[w][c][phys * 8 + (qd & 1) * 4] = pv[kt];
            }

            // ---- O^T += VT P^T (16x16x32) ----
#pragma unroll
            for (int ks = 0; ks < 4; ks++) {
                bf16x8 pf = *(const bf16x8*)&Ps[w][c][((ks * 4 + qd) ^ sw) * 8];
#pragma unroll
                for (int dt = 0; dt < 4; dt++) {
                    bf16x8 vf = *(const bf16x8*)&VTs[dt * 16 + c][((ks * 4 + qd) ^ sw) * 8];
                    O[dt] = __builtin_amdgcn_mfma_f32_16x16x32_bf16(vf, pf, O[dt], 0, 0, 0);
                }
            }
        }

        // ---- epilogue: y[qrow][h*64 + d], 8B vector stores ----
        const float inv_l = 1.0f / l_i;
#pragma unroll
        for (int dt = 0; dt < 4; dt++) {
            bf16x4 ov;
#pragma unroll
            for (int r = 0; r < 4; r++) ov[r] = (bf16r)(O[dt][r] * inv_l);
            *(bf16x4*)(y + (size_t)qrow * C_DIM + h * 64 + dt * 16 + qd * 4) = ov;
        }
    }
}

// ---------------------------------------------------------------------------
// launch.  Inputs f32, output f32.  ws peak = 56 MiB.
//
// Region timeline (all transitions stream-ordered, audited):
//   0..6   cwA        -> (dead after qkv gemm) -> rms2 [0..8] after proj
//   6..8   cwP        -> (needed by proj)      -> part of rms2
//   8..16  rms1/ctrs  -> (dead after qkv/attn) -> W1 -> (dead after w13) -> W2
//   16..40 qkv        -> (dead after attn)     -> W3 [16..24], h1 tail
//   40..48 VT         -> (dead after attn)     -> h1
//   48..56 y          -> (dead after proj)     -> h1
//   24..56 h1 [4096][4096] bf16 (32 MB), written by w13 after proj.
// ---------------------------------------------------------------------------
extern "C" void kernel_launch(void* const* d_in, const int* in_sizes, int n_in,
                              void* d_out, int out_size, void* d_ws, size_t ws_size,
                              hipStream_t stream) {
    const float* x        = (const float*)d_in[0];
    const float* attn_w   = (const float*)d_in[1];
    const float* ffn_w    = (const float*)d_in[2];
    const float* c_attn_w = (const float*)d_in[3];
    const float* c_proj_w = (const float*)d_in[4];
    const float* w1       = (const float*)d_in[5];
    const float* w2       = (const float*)d_in[6];
    const float* w3       = (const float*)d_in[7];
    float* xmid = (float*)d_out;

    char* ws = (char*)d_ws;
    bf16* cwA  = (bf16*)(ws);            // 0..6
    bf16* cwP  = (bf16*)(ws + MB(6));    // 6..8
    bf16* rms1 = (bf16*)(ws + MB(8));    // 8..16
    bf16* qkv  = (bf16*)(ws + MB(16));   // 16..40
    bf16* VT   = (bf16*)(ws + MB(40));   // 40..48
    bf16* y    = (bf16*)(ws + MB(48));   // 48..56
    int*  ctrs = (int*)(ws + MB(8));     // over rms1 (dead after qkv gemm)
    bf16* rms2 = (bf16*)(ws);            // 0..8 (over cwA/cwP, after proj)
    bf16* w1h  = (bf16*)(ws + MB(8));    // 8..16 (over rms1/ctrs, after attn)
    bf16* w3h  = (bf16*)(ws + MB(16));   // 16..24 (over qkv, after attn)
    bf16* w2h  = (bf16*)(ws + MB(8));    // 8..16 (over w1h, after w13)
    bf16* h1   = (bf16*)(ws + MB(24));   // 24..56 (over qkv tail/VT/y)

    // 1. attention weights -> bf16 (Q-proj rows x SCL: softmax scale folded)
    cvt_w<<<512, 256, 0, stream>>>(c_attn_w, 0, (ushort4*)cwA, 3072 * 1024 / 4,
                                   1024 * 1024 / 4, SCL);
    cvt_w<<<512, 256, 0, stream>>>(c_proj_w, 0, (ushort4*)cwP, 1024 * 1024 / 4, 0, 1.0f);
    // 2. rms1 = rmsnorm(x, attn_norm_w)
    rmsnorm_k<<<T_SEQ, 256, 0, stream>>>(x, attn_w, rms1);
    // 3. qkv = rms1 @ c_attn^T   [4096, 3072]
    gemm128<0, 0><<<dim3(24, 32), 256, 0, stream>>>(rms1, C_DIM, cwA, C_DIM, nullptr, qkv, 3072, 1024);
    // 4. VT (V transposed per head) + persistent-block flash attention v9
    build_tr<<<dim3(64, 16), 256, 0, stream>>>(qkv, VT, 2 * C_DIM);
    zero_ctr<<<1, 128, 0, stream>>>(ctrs);
    attn_mfma<<<768, 256, 0, stream>>>(qkv, VT, y, ctrs);
    // 5. FFN weight converts (regions dead after attn), xmid = x prefill
    cvt_w<<<512, 256, 0, stream>>>(w1, 0, (ushort4*)w1h, 4096 * 1024 / 4, 0, 1.0f);
    cvt_w<<<512, 256, 0, stream>>>(w3, 0, (ushort4*)w3h, 4096 * 1024 / 4, 0, 1.0f);
    copy_f32<<<2048, 256, 0, stream>>>((const float4*)x, (float4*)xmid, T_SEQ * C_DIM / 4);
    // 6. xmid += y @ c_proj^T   (split-K=2 atomic; 512 blocks = 2/CU)
    gemm128<4, 1><<<dim3(8, 32, 2), 256, 0, stream>>>(y, C_DIM, cwP, C_DIM, nullptr, xmid, 1024, 512);
    // 7. rms2 = rmsnorm(xmid, ffn_norm_w)   (into 0..8, cwA/cwP dead)
    rmsnorm_k<<<T_SEQ, 256, 0, stream>>>(xmid, ffn_w, rms2);
    // 8. h1 = silu(rms2@w1^T)*(rms2@w3^T), single pass N=4096 (1024 blocks)
    gemm_w13<<<dim3(32, 32), 256, 0, stream>>>(rms2, w1h, w3h, h1, 4096, 1024);
    // 9. xmid += h1 @ w2^T   (full K=4096, split-K=4 atomic; 1024 blocks)
    cvt_w<<<512, 256, 0, stream>>>(w2, 0, (ushort4*)w2h, 1024 * 4096 / 4, 0, 1.0f);
    gemm128<4, 1><<<dim3(8, 32, 4), 256, 0, stream>>>(h1, 4096, w2h, 4096, nullptr, xmid, 1024, 1024);
}